// Round 1
// baseline (5168.219 us; speedup 1.0000x reference)
//
#include <hip/hip_runtime.h>

// LAINRDecoder: fp32 baseline, multi-kernel.
// L=16384, B=4, M=256, HID=512, FDIM=128, INNER=128, HEADS=2, DH=64, NFREQ=16
#define L_N   16384
#define B_N   4
#define M_N   256
#define HID_N 512
#define PI_F  3.14159265358979323846f

__device__ __forceinline__ float omega_of(int jf, float lg) {
  float e = 1.0f + (float)jf * ((lg - 1.0f) * (1.0f / 15.0f));
  return powf(10.0f, e);
}

// gamma tile for 16 rows: gamma[r][f], f = c*32 + is_cos*16 + jf
__device__ __forceinline__ void fill_gamma16(float (*gamma)[132], const float* __restrict__ x,
                                             int l0, float lg, int tid) {
  for (int j = 0; j < 8; ++j) {
    int i = tid + 256 * j;
    int row = i >> 7, f = i & 127;
    int c = f >> 5, w = f & 31, jf = w & 15;
    float om = omega_of(jf, lg);
    float g = x[(size_t)(l0 + row) * 4 + c];
    float arg = (PI_F * g) * om;
    gamma[row][f] = (w >= 16) ? cosf(arg) : sinf(arg);
  }
}

// K1: x_q = relu(gamma_q @ w_query + b_query); q = x_q @ w_to_q; also t[l]
__global__ __launch_bounds__(256) void k_query(const float* __restrict__ x,
                                               const float* __restrict__ w_query,
                                               const float* __restrict__ b_query,
                                               const float* __restrict__ w_to_q,
                                               const int* dD, const int* dH, const int* dW, const int* dT,
                                               float lg,
                                               float* __restrict__ qbuf, float* __restrict__ tbuf) {
  __shared__ float gamma[16][132];
  __shared__ float xq[16][HID_N];
  int tid = threadIdx.x;
  int l0 = blockIdx.x * 16;
  fill_gamma16(gamma, x, l0, lg, tid);
  if (tid < 16) {
    int l = l0 + tid;
    float g0 = x[(size_t)l * 4 + 0], g1 = x[(size_t)l * 4 + 1];
    float g2 = x[(size_t)l * 4 + 2], g3 = x[(size_t)l * 4 + 3];
    int Dd = dD[0], Hh = dH[0], Ww = dW[0], Tt = dT[0];
    int zi = (int)(g0 * (float)Dd), yi = (int)(g1 * (float)Hh);
    int xi = (int)(g2 * (float)Ww), ti = (int)(g3 * (float)Tt);
    int idx = ((ti * Dd + zi) * Hh + yi) * Ww + xi;
    tbuf[l] = (float)idx / (float)(Dd * Hh * Ww * Tt);
  }
  __syncthreads();
  int r = tid >> 4, tc = tid & 15;
  for (int jj = 0; jj < 32; ++jj) {
    int n = tc + 16 * jj;
    float acc = b_query[n];
    for (int f = 0; f < 128; ++f) acc = fmaf(gamma[r][f], w_query[(size_t)f * HID_N + n], acc);
    xq[r][n] = fmaxf(acc, 0.0f);
  }
  __syncthreads();
  for (int jj = 0; jj < 8; ++jj) {
    int jq = tc + 16 * jj;  // 0..127
    float acc = 0.0f;
    for (int h = 0; h < HID_N; ++h) acc = fmaf(xq[r][h], w_to_q[(size_t)h * 128 + jq], acc);
    qbuf[(size_t)(l0 + r) * 128 + jq] = acc;
  }
}

// K2: hband[kk] = relu(gamma_band @ w_band[kk] + b_band[kk])   (precompute path)
__global__ __launch_bounds__(256) void k_band(const float* __restrict__ x,
                                              const float* __restrict__ wb,
                                              const float* __restrict__ bb,
                                              float lg, float* __restrict__ hb) {
  __shared__ float gamma[16][132];
  int tid = threadIdx.x;
  int l0 = blockIdx.x * 16;
  fill_gamma16(gamma, x, l0, lg, tid);
  __syncthreads();
  int r = tid >> 4, tc = tid & 15;
  for (int jj = 0; jj < 32; ++jj) {
    int n = tc + 16 * jj;
    float acc = bb[n];
    for (int f = 0; f < 128; ++f) acc = fmaf(gamma[r][f], wb[(size_t)f * HID_N + n], acc);
    hb[(size_t)(l0 + r) * HID_N + n] = fmaxf(acc, 0.0f);
  }
}

// K3: kv = tokens @ w_to_kv   (one block per (b,m) row; 256 output cols)
__global__ __launch_bounds__(256) void k_kv(const float* __restrict__ tokens,
                                            const float* __restrict__ w_to_kv,
                                            float* __restrict__ kv) {
  __shared__ float tok[HID_N];
  int row = blockIdx.x;  // b*256+m
  int tid = threadIdx.x;
  tok[tid] = tokens[(size_t)row * HID_N + tid];
  tok[tid + 256] = tokens[(size_t)row * HID_N + tid + 256];
  __syncthreads();
  float acc = 0.0f;
  for (int h = 0; h < HID_N; ++h) acc = fmaf(tok[h], w_to_kv[(size_t)h * 256 + tid], acc);
  kv[(size_t)row * 256 + tid] = acc;
}

// K4: attention (softmax over M=256) + modv = out @ w_to_out + b_to_out, per batch b
__global__ __launch_bounds__(256) void k_attn(const float* __restrict__ qbuf,
                                              const float* __restrict__ tbuf,
                                              const float* __restrict__ kvb,  // [M,256] of batch b
                                              const float* __restrict__ w_to_out,
                                              const float* __restrict__ b_to_out,
                                              float* __restrict__ modv) {    // [L,512] of batch b
  __shared__ float qt[16][132];
  __shared__ float sim[32][264];   // [(r*2+h)][m]
  __shared__ float chunk[32][132]; // k or v chunk; reused as out tile [16][132]
  __shared__ float trow[16];
  int tid = threadIdx.x;
  int l0 = blockIdx.x * 16;
  for (int j = 0; j < 8; ++j) {
    int i = tid + 256 * j;
    int row = i >> 7, col = i & 127;
    qt[row][col] = qbuf[(size_t)(l0 + row) * 128 + col];
  }
  if (tid < 16) trow[tid] = tbuf[l0 + tid];
  __syncthreads();
  // sim = q.k * 0.125 + bias
  for (int m0 = 0; m0 < 256; m0 += 32) {
    for (int j = 0; j < 16; ++j) {
      int i = tid + 256 * j;
      int row = i >> 7, col = i & 127;
      chunk[row][col] = kvb[(size_t)(m0 + row) * 256 + col];
    }
    __syncthreads();
    for (int p = tid; p < 512; p += 256) {
      int r = p >> 5, mi = p & 31;
      for (int h = 0; h < 2; ++h) {
        float acc = 0.0f;
        for (int d = 0; d < 64; d += 4) {
          float4 a = *(const float4*)&qt[r][h * 64 + d];
          float4 b = *(const float4*)&chunk[mi][h * 64 + d];
          acc += a.x * b.x + a.y * b.y + a.z * b.z + a.w * b.w;
        }
        float mp = ((float)(m0 + mi) + 0.5f) * (1.0f / 256.0f);
        float dd = trow[r] - mp;
        sim[r * 2 + h][m0 + mi] = acc * 0.125f - 10.0f * dd * dd;
      }
    }
    __syncthreads();
  }
  // softmax over m per (r,h): 32 rows, 8 threads each
  {
    int g = tid >> 3, sub = tid & 7;
    float mx = -1e30f;
    for (int m = sub; m < 256; m += 8) mx = fmaxf(mx, sim[g][m]);
    for (int off = 1; off < 8; off <<= 1) mx = fmaxf(mx, __shfl_xor(mx, off));
    float sum = 0.0f;
    for (int m = sub; m < 256; m += 8) { float e = __expf(sim[g][m] - mx); sim[g][m] = e; sum += e; }
    for (int off = 1; off < 8; off <<= 1) sum += __shfl_xor(sum, off);
    float inv = 1.0f / sum;
    for (int m = sub; m < 256; m += 8) sim[g][m] *= inv;
  }
  __syncthreads();
  // out = attn @ v
  int r2 = tid >> 4, tc = tid & 15;
  int c0 = tc * 8, h2 = c0 >> 6;
  float acc[8];
#pragma unroll
  for (int j = 0; j < 8; ++j) acc[j] = 0.0f;
  for (int m0 = 0; m0 < 256; m0 += 32) {
    for (int j = 0; j < 16; ++j) {
      int i = tid + 256 * j;
      int row = i >> 7, col = i & 127;
      chunk[row][col] = kvb[(size_t)(m0 + row) * 256 + 128 + col];
    }
    __syncthreads();
    for (int mi = 0; mi < 32; ++mi) {
      float a = sim[r2 * 2 + h2][m0 + mi];
      float4 v0 = *(const float4*)&chunk[mi][c0];
      float4 v1 = *(const float4*)&chunk[mi][c0 + 4];
      acc[0] = fmaf(a, v0.x, acc[0]); acc[1] = fmaf(a, v0.y, acc[1]);
      acc[2] = fmaf(a, v0.z, acc[2]); acc[3] = fmaf(a, v0.w, acc[3]);
      acc[4] = fmaf(a, v1.x, acc[4]); acc[5] = fmaf(a, v1.y, acc[5]);
      acc[6] = fmaf(a, v1.z, acc[6]); acc[7] = fmaf(a, v1.w, acc[7]);
    }
    __syncthreads();
  }
  float(*ot)[132] = (float(*)[132])chunk;
#pragma unroll
  for (int j = 0; j < 8; ++j) ot[r2][c0 + j] = acc[j];
  __syncthreads();
  // modv = out @ w_to_out + b_to_out
  for (int jj = 0; jj < 32; ++jj) {
    int n = tc + 16 * jj;
    float a2 = b_to_out[n];
    for (int c = 0; c < 128; ++c) a2 = fmaf(ot[r2][c], w_to_out[(size_t)c * HID_N + n], a2);
    modv[(size_t)(l0 + r2) * HID_N + n] = a2;
  }
}

// K5: C = relu(A(+A2) @ W + bias (+addend) (+ relu(gamma@w_band+b_band)))
// A:[L,512] W:[512,512] row-major; 64x64 tile, K-chunk 16
__global__ __launch_bounds__(256) void k_gemm512(const float* __restrict__ A,
                                                 const float* __restrict__ A2,
                                                 const float* __restrict__ W,
                                                 const float* __restrict__ bias,
                                                 const float* __restrict__ addend,
                                                 const float* __restrict__ xg,
                                                 const float* __restrict__ w_band_k,
                                                 const float* __restrict__ b_band_k,
                                                 float lg,
                                                 float* __restrict__ C) {
  __shared__ float As[16][68];
  __shared__ float Ws[16][68];
  __shared__ float gm[64][132];
  int tid = threadIdx.x;
  int n0 = blockIdx.x * 64, r0 = blockIdx.y * 64;
  int ty = tid >> 4, tx = tid & 15;
  if (w_band_k) {  // fused band path: gamma for 64 rows
    for (int j = 0; j < 32; ++j) {
      int i = tid + 256 * j;
      int row = i >> 7, f = i & 127;
      int c = f >> 5, w = f & 31, jf = w & 15;
      float om = omega_of(jf, lg);
      float g = xg[(size_t)(r0 + row) * 4 + c];
      float arg = (PI_F * g) * om;
      gm[row][f] = (w >= 16) ? cosf(arg) : sinf(arg);
    }
  }
  float acc[4][4];
#pragma unroll
  for (int i = 0; i < 4; ++i)
#pragma unroll
    for (int j = 0; j < 4; ++j) acc[i][j] = 0.0f;

  for (int k0 = 0; k0 < HID_N; k0 += 16) {
    {
      int row = tid >> 2, kk0 = (tid & 3) * 4;
      float4 a = *(const float4*)&A[(size_t)(r0 + row) * HID_N + k0 + kk0];
      if (A2) {
        float4 a2 = *(const float4*)&A2[(size_t)(r0 + row) * HID_N + k0 + kk0];
        a.x += a2.x; a.y += a2.y; a.z += a2.z; a.w += a2.w;
      }
      As[kk0 + 0][row] = a.x; As[kk0 + 1][row] = a.y;
      As[kk0 + 2][row] = a.z; As[kk0 + 3][row] = a.w;
      int kk = tid >> 4, nn = (tid & 15) * 4;
      float4 wv = *(const float4*)&W[(size_t)(k0 + kk) * HID_N + n0 + nn];
      *(float4*)&Ws[kk][nn] = wv;
    }
    __syncthreads();
#pragma unroll
    for (int kk = 0; kk < 16; ++kk) {
      float4 a4 = *(const float4*)&As[kk][ty * 4];
      float4 b4 = *(const float4*)&Ws[kk][tx * 4];
      float av[4] = {a4.x, a4.y, a4.z, a4.w};
      float bv[4] = {b4.x, b4.y, b4.z, b4.w};
#pragma unroll
      for (int i = 0; i < 4; ++i)
#pragma unroll
        for (int j = 0; j < 4; ++j) acc[i][j] = fmaf(av[i], bv[j], acc[i][j]);
    }
    __syncthreads();
  }
  // band term (fused path)
  float bandv[4][4];
  if (w_band_k) {
#pragma unroll
    for (int j = 0; j < 4; ++j) {
      int n = n0 + tx * 4 + j;
      float bd[4];
#pragma unroll
      for (int i = 0; i < 4; ++i) bd[i] = b_band_k[n];
      for (int f = 0; f < 128; ++f) {
        float wv = w_band_k[(size_t)f * HID_N + n];
#pragma unroll
        for (int i = 0; i < 4; ++i) bd[i] = fmaf(gm[ty * 4 + i][f], wv, bd[i]);
      }
#pragma unroll
      for (int i = 0; i < 4; ++i) bandv[i][j] = fmaxf(bd[i], 0.0f);
    }
  }
#pragma unroll
  for (int i = 0; i < 4; ++i) {
    int grow = r0 + ty * 4 + i;
#pragma unroll
    for (int j = 0; j < 4; ++j) {
      int n = n0 + tx * 4 + j;
      float v = acc[i][j] + bias[n];
      if (addend) v += addend[(size_t)grow * HID_N + n];
      if (w_band_k) v += bandv[i][j];
      C[(size_t)grow * HID_N + n] = fmaxf(v, 0.0f);
    }
  }
}

// K6: out(+)= hv @ w_out[kk] + b_out[kk]; 4 rows/block, 64 lanes per row
__global__ __launch_bounds__(256) void k_out(const float* __restrict__ hv,
                                             const float* __restrict__ w_out_k,
                                             const float* __restrict__ b_out_k,
                                             float* __restrict__ out_b, int init) {
  int tid = threadIdx.x;
  int l = blockIdx.x * 4 + (tid >> 6);
  int lane = tid & 63;
  float a0 = 0.0f, a1 = 0.0f, a2 = 0.0f;
  for (int h = lane; h < HID_N; h += 64) {
    float a = hv[(size_t)l * HID_N + h];
    a0 = fmaf(a, w_out_k[h * 3 + 0], a0);
    a1 = fmaf(a, w_out_k[h * 3 + 1], a1);
    a2 = fmaf(a, w_out_k[h * 3 + 2], a2);
  }
  for (int off = 32; off; off >>= 1) {
    a0 += __shfl_down(a0, off);
    a1 += __shfl_down(a1, off);
    a2 += __shfl_down(a2, off);
  }
  if (lane == 0) {
    float* p = &out_b[(size_t)l * 3];
    if (init) {
      p[0] = a0 + b_out_k[0]; p[1] = a1 + b_out_k[1]; p[2] = a2 + b_out_k[2];
    } else {
      p[0] += a0 + b_out_k[0]; p[1] += a1 + b_out_k[1]; p[2] += a2 + b_out_k[2];
    }
  }
}

extern "C" void kernel_launch(void* const* d_in, const int* in_sizes, int n_in,
                              void* d_out, int out_size, void* d_ws, size_t ws_size,
                              hipStream_t stream) {
  const float* x        = (const float*)d_in[0];
  const float* tokens   = (const float*)d_in[1];
  const float* w_query  = (const float*)d_in[2];
  const float* b_query  = (const float*)d_in[3];
  const float* w_to_q   = (const float*)d_in[4];
  const float* w_to_kv  = (const float*)d_in[5];
  const float* w_to_out = (const float*)d_in[6];
  const float* b_to_out = (const float*)d_in[7];
  const float* w_band   = (const float*)d_in[8];
  const float* b_band   = (const float*)d_in[9];
  const float* w_mod    = (const float*)d_in[10];
  const float* b_mod    = (const float*)d_in[11];
  const float* w_hv     = (const float*)d_in[12];
  const float* b_hv     = (const float*)d_in[13];
  const float* w_out    = (const float*)d_in[14];
  const float* b_out    = (const float*)d_in[15];
  const int* Dd = (const int*)d_in[16];
  const int* Hh = (const int*)d_in[17];
  const int* Ww = (const int*)d_in[18];
  const int* Tt = (const int*)d_in[19];
  float* out = (float*)d_out;
  float* ws = (float*)d_ws;

  const float LG_Q = 2.1072099696478683f;  // log10(128)
  const float LG_B[3] = {2.1072099696478683f, 1.5051499783199058f, 0.9030899869919435f};

  size_t off = 0;
  float* qbuf = ws; off += (size_t)L_N * 128;
  float* tbuf = ws + off; off += L_N;
  float* kvbuf = ws + off; off += (size_t)B_N * M_N * 256;
  size_t big = (size_t)L_N * HID_N;  // 8M floats
  // precompute-hband path needs 3 extra big buffers
  bool use_pre = ws_size >= (off + 7 * big) * sizeof(float);
  float* hband = nullptr;
  if (use_pre) { hband = ws + off; off += 3 * big; }
  float* modv = ws + off; off += big;
  float* mbuf = ws + off; off += big;
  float* hva = ws + off; off += big;
  float* hvb = ws + off; off += big;

  k_query<<<dim3(L_N / 16), 256, 0, stream>>>(x, w_query, b_query, w_to_q, Dd, Hh, Ww, Tt, LG_Q, qbuf, tbuf);
  if (use_pre) {
    for (int kk = 0; kk < 3; ++kk)
      k_band<<<dim3(L_N / 16), 256, 0, stream>>>(x, w_band + (size_t)kk * 128 * HID_N,
                                                 b_band + kk * HID_N, LG_B[kk], hband + kk * big);
  }
  k_kv<<<dim3(B_N * M_N), 256, 0, stream>>>(tokens, w_to_kv, kvbuf);

  for (int b = 0; b < B_N; ++b) {
    k_attn<<<dim3(L_N / 16), 256, 0, stream>>>(qbuf, tbuf, kvbuf + (size_t)b * M_N * 256,
                                               w_to_out, b_to_out, modv);
    float* hv_cur = hva;
    for (int kk = 0; kk < 3; ++kk) {
      const float* wm = w_mod + (size_t)kk * HID_N * HID_N;
      const float* bm = b_mod + kk * HID_N;
      if (kk == 0) {
        if (use_pre)
          k_gemm512<<<dim3(8, L_N / 64), 256, 0, stream>>>(modv, nullptr, wm, bm, hband,
                                                           nullptr, nullptr, nullptr, 0.0f, hva);
        else
          k_gemm512<<<dim3(8, L_N / 64), 256, 0, stream>>>(modv, nullptr, wm, bm, nullptr,
                                                           x, w_band, b_band, LG_B[0], hva);
        hv_cur = hva;
      } else {
        if (use_pre)
          k_gemm512<<<dim3(8, L_N / 64), 256, 0, stream>>>(modv, nullptr, wm, bm, hband + kk * big,
                                                           nullptr, nullptr, nullptr, 0.0f, mbuf);
        else
          k_gemm512<<<dim3(8, L_N / 64), 256, 0, stream>>>(modv, nullptr, wm, bm, nullptr,
                                                           x, w_band + (size_t)kk * 128 * HID_N,
                                                           b_band + kk * HID_N, LG_B[kk], mbuf);
        float* dst = (kk == 1) ? hvb : hva;
        k_gemm512<<<dim3(8, L_N / 64), 256, 0, stream>>>(mbuf, hv_cur,
                                                         w_hv + (size_t)(kk - 1) * HID_N * HID_N,
                                                         b_hv + (kk - 1) * HID_N, nullptr,
                                                         nullptr, nullptr, nullptr, 0.0f, dst);
        hv_cur = dst;
      }
      k_out<<<dim3(L_N / 4), 256, 0, stream>>>(hv_cur, w_out + (size_t)kk * HID_N * 3,
                                               b_out + kk * 3, out + (size_t)b * L_N * 3,
                                               kk == 0 ? 1 : 0);
    }
  }
}

// Round 2
// 1137.880 us; speedup vs baseline: 4.5420x; 4.5420x over previous
//
#include <hip/hip_runtime.h>

#define L_N   16384
#define B_N   4
#define M_N   256
#define HID_N 512
#define PI_F  3.14159265358979323846f

typedef short short8 __attribute__((ext_vector_type(8)));
typedef float f32x4 __attribute__((ext_vector_type(4)));

__device__ __forceinline__ ushort f2bf(float f) {
  uint u = __float_as_uint(f);
  uint r = u + 0x7FFF + ((u >> 16) & 1);
  return (ushort)(r >> 16);
}
__device__ __forceinline__ float bf2f(ushort s) {
  return __uint_as_float(((uint)s) << 16);
}
__device__ __forceinline__ void gld_lds16(const void* g, void* s) {
  __builtin_amdgcn_global_load_lds((const __attribute__((address_space(1))) void*)g,
                                   (__attribute__((address_space(3))) void*)s, 16, 0, 0);
}

// ---------- prep: transpose fp32 [R][C] -> bf16 [C][R] ----------
__global__ __launch_bounds__(256) void k_wt(const float* __restrict__ in,
                                            ushort* __restrict__ out, int R, int C) {
  __shared__ float t[32][33];
  int bx = blockIdx.x * 32, by = blockIdx.y * 32;
  int tx = threadIdx.x & 31, ty = threadIdx.x >> 5;
#pragma unroll
  for (int j = 0; j < 32; j += 8) t[ty + j][tx] = in[(size_t)(by + ty + j) * C + bx + tx];
  __syncthreads();
#pragma unroll
  for (int j = 0; j < 32; j += 8)
    out[(size_t)(bx + ty + j) * R + by + tx] = f2bf(t[tx][ty + j]);
}

// ---------- prep: fp32 -> bf16 elementwise ----------
__global__ __launch_bounds__(256) void k_cvt(const float* __restrict__ in,
                                             ushort* __restrict__ out, int n4) {
  int i = blockIdx.x * 256 + threadIdx.x;
  if (i >= n4) return;
  float4 v = *(const float4*)&in[(size_t)i * 4];
  ushort* o = &out[(size_t)i * 4];
  o[0] = f2bf(v.x); o[1] = f2bf(v.y); o[2] = f2bf(v.z); o[3] = f2bf(v.w);
}

// ---------- gamma: [4 specs][L][128] bf16 ----------
__global__ __launch_bounds__(256) void k_gamma(const float* __restrict__ x,
                                               ushort* __restrict__ gout) {
  __shared__ float om[16];
  const float lgs[4] = {2.1072099696478683f, 2.1072099696478683f,
                        1.5051499783199058f, 0.9030899869919435f};
  int spec = blockIdx.y;
  float lg = lgs[spec];
  int tid = threadIdx.x;
  if (tid < 16) om[tid] = powf(10.0f, 1.0f + (float)tid * ((lg - 1.0f) * (1.0f / 15.0f)));
  __syncthreads();
  int l0 = blockIdx.x * 16;
  int idx0 = tid * 8;
  int row = idx0 >> 7, f0 = idx0 & 127;
  int c = f0 >> 5;
  float g = x[(size_t)(l0 + row) * 4 + c];
  float base = PI_F * g;
  int w0 = f0 & 31;
  bool is_cos = (w0 >= 16);
  short8 o;
#pragma unroll
  for (int j = 0; j < 8; ++j) {
    int jf = (w0 + j) & 15;
    float arg = base * om[jf];
    float v = is_cos ? __cosf(arg) : __sinf(arg);
    o[j] = (short)f2bf(v);
  }
  *(short8*)&gout[(size_t)spec * L_N * 128 + (size_t)(l0 + row) * 128 + f0] = o;
}

// ---------- t positions ----------
__global__ __launch_bounds__(256) void k_tpos(const float* __restrict__ x,
                                              const int* dD, const int* dH,
                                              const int* dW, const int* dT,
                                              float* __restrict__ tbuf) {
  int l = blockIdx.x * 256 + threadIdx.x;
  float g0 = x[(size_t)l * 4 + 0], g1 = x[(size_t)l * 4 + 1];
  float g2 = x[(size_t)l * 4 + 2], g3 = x[(size_t)l * 4 + 3];
  int Dd = dD[0], Hh = dH[0], Ww = dW[0], Tt = dT[0];
  int zi = (int)(g0 * (float)Dd), yi = (int)(g1 * (float)Hh);
  int xi = (int)(g2 * (float)Ww), ti = (int)(g3 * (float)Tt);
  int idx = ((ti * Dd + zi) * Hh + yi) * Ww + xi;
  tbuf[l] = (float)idx / (float)(Dd * Hh * Ww * Tt);
}

// ---------- generic bf16 MFMA GEMM ----------
// C[M][N] = ep(A[M][K] @ Wt[N][K]^T); 128x128 tile, BK=64, 4 waves (2x2)
__global__ __launch_bounds__(256) void k_gemm(const ushort* __restrict__ A,
                                              const ushort* __restrict__ Wt,
                                              const float* __restrict__ bias,
                                              const ushort* __restrict__ add1,  // pre-relu
                                              const ushort* __restrict__ add2,  // post-relu
                                              ushort* __restrict__ C,
                                              int M, int N, int K, int do_relu) {
  __shared__ __align__(16) ushort As[128 * 64];
  __shared__ __align__(16) ushort Ws[128 * 64];
  int tid = threadIdx.x;
  int lane = tid & 63, wid = tid >> 6;
  int n0 = blockIdx.x * 128, r0 = blockIdx.y * 128;
  int wr = wid >> 1, wc = wid & 1;
  f32x4 acc[4][4];
#pragma unroll
  for (int i = 0; i < 4; ++i)
#pragma unroll
    for (int j = 0; j < 4; ++j) acc[i][j] = (f32x4)0.0f;

  for (int k0 = 0; k0 < K; k0 += 64) {
#pragma unroll
    for (int j = 0; j < 4; ++j) {
      int sig = j * 256 + wid * 64 + lane;
      int r = sig >> 3, ph = sig & 7, sl = ph ^ (r & 7);
      gld_lds16(&A[(size_t)(r0 + r) * K + k0 + sl * 8], &As[(size_t)(j * 256 + wid * 64) * 8]);
      gld_lds16(&Wt[(size_t)(n0 + r) * K + k0 + sl * 8], &Ws[(size_t)(j * 256 + wid * 64) * 8]);
    }
    __syncthreads();
#pragma unroll
    for (int ks = 0; ks < 2; ++ks) {
      short8 af[4], bf[4];
#pragma unroll
      for (int fm = 0; fm < 4; ++fm) {
        int row = wr * 64 + fm * 16 + (lane & 15);
        af[fm] = *(const short8*)&As[row * 64 + (((ks * 4 + (lane >> 4)) ^ (row & 7)) * 8)];
      }
#pragma unroll
      for (int fn = 0; fn < 4; ++fn) {
        int nl = wc * 64 + fn * 16 + (lane & 15);
        bf[fn] = *(const short8*)&Ws[nl * 64 + (((ks * 4 + (lane >> 4)) ^ (nl & 7)) * 8)];
      }
#pragma unroll
      for (int fm = 0; fm < 4; ++fm)
#pragma unroll
        for (int fn = 0; fn < 4; ++fn)
          acc[fm][fn] = __builtin_amdgcn_mfma_f32_16x16x32_bf16(af[fm], bf[fn], acc[fm][fn], 0, 0, 0);
    }
    __syncthreads();
  }
  // epilogue
#pragma unroll
  for (int fm = 0; fm < 4; ++fm) {
#pragma unroll
    for (int reg = 0; reg < 4; ++reg) {
      size_t rg = (size_t)(r0 + wr * 64 + fm * 16 + (lane >> 4) * 4 + reg);
#pragma unroll
      for (int fn = 0; fn < 4; ++fn) {
        int ng = n0 + wc * 64 + fn * 16 + (lane & 15);
        float v = acc[fm][fn][reg];
        if (bias) v += bias[ng];
        if (add1) v += bf2f(add1[rg * N + ng]);
        if (do_relu) v = fmaxf(v, 0.0f);
        if (add2) v += bf2f(add2[rg * N + ng]);
        C[rg * N + ng] = f2bf(v);
      }
    }
  }
}

// ---------- kv rearrange: kvtmp [B*256][256] -> kbuf [B][256][128], vtb [B][128][256] ----------
__global__ __launch_bounds__(256) void k_rearr(const ushort* __restrict__ kvtmp,
                                               ushort* __restrict__ kbuf,
                                               ushort* __restrict__ vtb) {
  int i = blockIdx.x * 256 + threadIdx.x;  // < 262144
  int col = i & 255, row = i >> 8;
  int b = row >> 8, m = row & 255;
  ushort v = kvtmp[i];
  if (col < 128)
    kbuf[((size_t)b * 256 + m) * 128 + col] = v;
  else
    vtb[(size_t)b * 128 * 256 + (size_t)(col - 128) * 256 + m] = v;
}

// ---------- MFMA attention per (b, head): Q-tile 64 rows ----------
__global__ __launch_bounds__(256) void k_attn_m(const ushort* __restrict__ qbuf,
                                                const float* __restrict__ tbuf,
                                                const ushort* __restrict__ kbuf_b,   // [256][128]
                                                const ushort* __restrict__ vtb_b,    // [128][256]
                                                ushort* __restrict__ attn) {         // [L][128]
  __shared__ __align__(16) ushort Kt[256 * 64];
  __shared__ __align__(16) ushort Vt[64 * 256];
  __shared__ __align__(16) ushort Qs[64 * 64];
  __shared__ __align__(16) ushort Pw[4][16 * 40];
  __shared__ float ts[64];
  int tid = threadIdx.x;
  int lane = tid & 63, wid = tid >> 6;
  int l0 = blockIdx.x * 64;
  int h = blockIdx.y;
  // stage K [256 m][64 d] (row stride 128B, xor swizzle by (m&7))
#pragma unroll
  for (int j = 0; j < 8; ++j) {
    int sig = j * 256 + wid * 64 + lane;
    int m = sig >> 3, ph = sig & 7, sl = ph ^ (m & 7);
    gld_lds16(&kbuf_b[(size_t)m * 128 + h * 64 + sl * 8], &Kt[(size_t)(j * 256 + wid * 64) * 8]);
  }
  // stage Vt [64 d][256 m] (row stride 512B, swizzle slot ^ ((d&7)<<2))
#pragma unroll
  for (int j = 0; j < 8; ++j) {
    int sig = j * 256 + wid * 64 + lane;
    int d = sig >> 5, ph = sig & 31, sl = ph ^ ((d & 7) << 2);
    gld_lds16(&vtb_b[(size_t)(h * 64 + d) * 256 + sl * 8], &Vt[(size_t)(j * 256 + wid * 64) * 8]);
  }
  // stage Q [64 q][64 d]
#pragma unroll
  for (int j = 0; j < 2; ++j) {
    int sig = j * 256 + wid * 64 + lane;
    int q = sig >> 3, ph = sig & 7, sl = ph ^ (q & 7);
    gld_lds16(&qbuf[(size_t)(l0 + q) * 128 + h * 64 + sl * 8], &Qs[(size_t)(j * 256 + wid * 64) * 8]);
  }
  if (tid < 64) ts[tid] = tbuf[l0 + tid];
  __syncthreads();

  // sim = Q@K^T : wave w owns q-rows w*16..+15, acc over 16 m-tiles
  f32x4 s_acc[16];
#pragma unroll
  for (int fn = 0; fn < 16; ++fn) s_acc[fn] = (f32x4)0.0f;
#pragma unroll
  for (int ks = 0; ks < 2; ++ks) {
    int qrow = wid * 16 + (lane & 15);
    short8 aq = *(const short8*)&Qs[qrow * 64 + (((ks * 4 + (lane >> 4)) ^ (qrow & 7)) * 8)];
#pragma unroll
    for (int fn = 0; fn < 16; ++fn) {
      int m = fn * 16 + (lane & 15);
      short8 bk = *(const short8*)&Kt[m * 64 + (((ks * 4 + (lane >> 4)) ^ (m & 7)) * 8)];
      s_acc[fn] = __builtin_amdgcn_mfma_f32_16x16x32_bf16(aq, bk, s_acc[fn], 0, 0, 0);
    }
  }
  // scale + bias, softmax over m (rows live on (lane&15)-groups x fn)
  float mx[4] = {-1e30f, -1e30f, -1e30f, -1e30f};
#pragma unroll
  for (int fn = 0; fn < 16; ++fn) {
#pragma unroll
    for (int reg = 0; reg < 4; ++reg) {
      int ql = wid * 16 + (lane >> 4) * 4 + reg;
      int m = fn * 16 + (lane & 15);
      float mp = ((float)m + 0.5f) * (1.0f / 256.0f);
      float d = ts[ql] - mp;
      float v = s_acc[fn][reg] * 0.125f - 10.0f * d * d;
      s_acc[fn][reg] = v;
      mx[reg] = fmaxf(mx[reg], v);
    }
  }
#pragma unroll
  for (int reg = 0; reg < 4; ++reg) {
    mx[reg] = fmaxf(mx[reg], __shfl_xor(mx[reg], 1));
    mx[reg] = fmaxf(mx[reg], __shfl_xor(mx[reg], 2));
    mx[reg] = fmaxf(mx[reg], __shfl_xor(mx[reg], 4));
    mx[reg] = fmaxf(mx[reg], __shfl_xor(mx[reg], 8));
  }
  float sm[4] = {0.0f, 0.0f, 0.0f, 0.0f};
#pragma unroll
  for (int fn = 0; fn < 16; ++fn) {
#pragma unroll
    for (int reg = 0; reg < 4; ++reg) {
      float e = __expf(s_acc[fn][reg] - mx[reg]);
      s_acc[fn][reg] = e;
      sm[reg] += e;
    }
  }
#pragma unroll
  for (int reg = 0; reg < 4; ++reg) {
    sm[reg] += __shfl_xor(sm[reg], 1);
    sm[reg] += __shfl_xor(sm[reg], 2);
    sm[reg] += __shfl_xor(sm[reg], 4);
    sm[reg] += __shfl_xor(sm[reg], 8);
  }
  float inv[4];
#pragma unroll
  for (int reg = 0; reg < 4; ++reg) inv[reg] = 1.0f / sm[reg];

  // PV in chunks of 32 m: P chunk -> wave-local LDS -> A-frag
  f32x4 o_acc[4];
#pragma unroll
  for (int fn = 0; fn < 4; ++fn) o_acc[fn] = (f32x4)0.0f;
  for (int kk = 0; kk < 8; ++kk) {
#pragma unroll
    for (int fp = 0; fp < 2; ++fp) {
      int fn = kk * 2 + fp;
#pragma unroll
      for (int reg = 0; reg < 4; ++reg) {
        int ql16 = (lane >> 4) * 4 + reg;
        int mc = fp * 16 + (lane & 15);
        Pw[wid][ql16 * 40 + mc] = f2bf(s_acc[fn][reg] * inv[reg]);
      }
    }
    asm volatile("s_waitcnt lgkmcnt(0)" ::: "memory");
    __builtin_amdgcn_sched_barrier(0);
    short8 pa = *(const short8*)&Pw[wid][(lane & 15) * 40 + (lane >> 4) * 8];
#pragma unroll
    for (int fn = 0; fn < 4; ++fn) {
      int dr = fn * 16 + (lane & 15);
      short8 vb = *(const short8*)&Vt[dr * 256 + (((kk * 4 + (lane >> 4)) ^ ((dr & 7) << 2)) * 8)];
      o_acc[fn] = __builtin_amdgcn_mfma_f32_16x16x32_bf16(pa, vb, o_acc[fn], 0, 0, 0);
    }
    asm volatile("s_waitcnt lgkmcnt(0)" ::: "memory");
    __builtin_amdgcn_sched_barrier(0);
  }
#pragma unroll
  for (int fn = 0; fn < 4; ++fn)
#pragma unroll
    for (int reg = 0; reg < 4; ++reg) {
      int ql = l0 + wid * 16 + (lane >> 4) * 4 + reg;
      attn[(size_t)ql * 128 + h * 64 + fn * 16 + (lane & 15)] = f2bf(o_acc[fn][reg]);
    }
}

// ---------- out accumulation: out (+)= hv @ w_out[kk] + b_out[kk] ----------
__global__ __launch_bounds__(256) void k_out(const ushort* __restrict__ hv,
                                             const float* __restrict__ wo,
                                             const float* __restrict__ bo,
                                             float* __restrict__ outp, int init) {
  int tid = threadIdx.x;
  int l = blockIdx.x * 4 + (tid >> 6);
  int lane = tid & 63;
  short8 v = *(const short8*)&hv[(size_t)l * HID_N + lane * 8];
  float a0 = 0.0f, a1 = 0.0f, a2 = 0.0f;
#pragma unroll
  for (int j = 0; j < 8; ++j) {
    float a = bf2f((ushort)v[j]);
    int hh = lane * 8 + j;
    a0 = fmaf(a, wo[hh * 3 + 0], a0);
    a1 = fmaf(a, wo[hh * 3 + 1], a1);
    a2 = fmaf(a, wo[hh * 3 + 2], a2);
  }
  for (int off = 32; off; off >>= 1) {
    a0 += __shfl_down(a0, off);
    a1 += __shfl_down(a1, off);
    a2 += __shfl_down(a2, off);
  }
  if (lane == 0) {
    float* p = &outp[(size_t)l * 3];
    if (init) { p[0] = a0 + bo[0]; p[1] = a1 + bo[1]; p[2] = a2 + bo[2]; }
    else      { p[0] += a0 + bo[0]; p[1] += a1 + bo[1]; p[2] += a2 + bo[2]; }
  }
}

extern "C" void kernel_launch(void* const* d_in, const int* in_sizes, int n_in,
                              void* d_out, int out_size, void* d_ws, size_t ws_size,
                              hipStream_t stream) {
  const float* x        = (const float*)d_in[0];
  const float* tokens   = (const float*)d_in[1];
  const float* w_query  = (const float*)d_in[2];
  const float* b_query  = (const float*)d_in[3];
  const float* w_to_q   = (const float*)d_in[4];
  const float* w_to_kv  = (const float*)d_in[5];
  const float* w_to_out = (const float*)d_in[6];
  const float* b_to_out = (const float*)d_in[7];
  const float* w_band   = (const float*)d_in[8];
  const float* b_band   = (const float*)d_in[9];
  const float* w_mod    = (const float*)d_in[10];
  const float* b_mod    = (const float*)d_in[11];
  const float* w_hv     = (const float*)d_in[12];
  const float* b_hv     = (const float*)d_in[13];
  const float* w_out    = (const float*)d_in[14];
  const float* b_out    = (const float*)d_in[15];
  const int* Dd = (const int*)d_in[16];
  const int* Hh = (const int*)d_in[17];
  const int* Ww = (const int*)d_in[18];
  const int* Tt = (const int*)d_in[19];
  float* out = (float*)d_out;

  ushort* W = (ushort*)d_ws;
  size_t o = 0;
  const size_t big = (size_t)L_N * HID_N;        // 8388608
  ushort* gamma = W + o; o += 4 * (size_t)L_N * 128;   // region A; reused as hva
  ushort* hva = gamma;
  ushort* xq = W + o; o += big;                  // region B; reused as mbuf
  ushort* mbuf = xq;
  ushort* qb = W + o; o += (size_t)L_N * 128;
  ushort* hband = W + o; o += 3 * big;
  ushort* modv = W + o; o += big;
  ushort* hvb = W + o; o += big;
  ushort* attn = W + o; o += (size_t)L_N * 128;  // also kvtmp (262144 <= 2097152)
  ushort* kvtmp = attn;
  ushort* tokb = W + o; o += (size_t)B_N * M_N * HID_N;
  ushort* kbuf = W + o; o += (size_t)B_N * M_N * 128;
  ushort* vtb = W + o; o += (size_t)B_N * 128 * M_N;
  ushort* wq_t = W + o; o += 512 * 128;
  ushort* wtq_t = W + o; o += 128 * 512;
  ushort* wkv_t = W + o; o += 256 * 512;
  ushort* wto_t = W + o; o += 512 * 128;
  ushort* wb_t = W + o; o += 3 * 512 * 128;
  ushort* wm_t = W + o; o += 3 * 512 * 512;
  ushort* whv_t = W + o; o += 2 * 512 * 512;
  if (o & 1) o += 1;
  float* tbuf = (float*)(W + o);

  // ---- prep ----
  k_wt<<<dim3(16, 4), 256, 0, stream>>>(w_query, wq_t, 128, 512);
  k_wt<<<dim3(4, 16), 256, 0, stream>>>(w_to_q, wtq_t, 512, 128);
  k_wt<<<dim3(8, 16), 256, 0, stream>>>(w_to_kv, wkv_t, 512, 256);
  k_wt<<<dim3(16, 4), 256, 0, stream>>>(w_to_out, wto_t, 128, 512);
  for (int kk = 0; kk < 3; ++kk) {
    k_wt<<<dim3(16, 4), 256, 0, stream>>>(w_band + (size_t)kk * 128 * 512, wb_t + (size_t)kk * 512 * 128, 128, 512);
    k_wt<<<dim3(16, 16), 256, 0, stream>>>(w_mod + (size_t)kk * 512 * 512, wm_t + (size_t)kk * 512 * 512, 512, 512);
  }
  for (int kk = 0; kk < 2; ++kk)
    k_wt<<<dim3(16, 16), 256, 0, stream>>>(w_hv + (size_t)kk * 512 * 512, whv_t + (size_t)kk * 512 * 512, 512, 512);
  k_cvt<<<dim3(512), 256, 0, stream>>>(tokens, tokb, B_N * M_N * HID_N / 4);
  k_gamma<<<dim3(L_N / 16, 4), 256, 0, stream>>>(x, gamma);
  k_tpos<<<dim3(L_N / 256), 256, 0, stream>>>(x, Dd, Hh, Ww, Tt, tbuf);

  // ---- shared pre-pass ----
  k_gemm<<<dim3(4, L_N / 128), 256, 0, stream>>>(gamma, wq_t, b_query, nullptr, nullptr, xq, L_N, 512, 128, 1);
  k_gemm<<<dim3(1, L_N / 128), 256, 0, stream>>>(xq, wtq_t, nullptr, nullptr, nullptr, qb, L_N, 128, 512, 0);
  for (int kk = 0; kk < 3; ++kk)
    k_gemm<<<dim3(4, L_N / 128), 256, 0, stream>>>(gamma + (size_t)(1 + kk) * L_N * 128,
                                                   wb_t + (size_t)kk * 512 * 128,
                                                   b_band + kk * 512, nullptr, nullptr,
                                                   hband + (size_t)kk * big, L_N, 512, 128, 1);
  k_gemm<<<dim3(2, 8), 256, 0, stream>>>(tokb, wkv_t, nullptr, nullptr, nullptr, kvtmp, 1024, 256, 512, 0);
  k_rearr<<<dim3(1024), 256, 0, stream>>>(kvtmp, kbuf, vtb);

  // ---- per-batch ----
  for (int b = 0; b < B_N; ++b) {
    k_attn_m<<<dim3(L_N / 64, 2), 256, 0, stream>>>(qb, tbuf,
                                                    kbuf + (size_t)b * M_N * 128,
                                                    vtb + (size_t)b * 128 * M_N, attn);
    k_gemm<<<dim3(4, L_N / 128), 256, 0, stream>>>(attn, wto_t, b_to_out, nullptr, nullptr, modv, L_N, 512, 128, 0);
    // kk=0
    k_gemm<<<dim3(4, L_N / 128), 256, 0, stream>>>(modv, wm_t, b_mod, hband, nullptr, hva, L_N, 512, 512, 1);
    k_out<<<dim3(L_N / 4), 256, 0, stream>>>(hva, w_out, b_out, out + (size_t)b * L_N * 3, 1);
    // kk=1
    k_gemm<<<dim3(4, L_N / 128), 256, 0, stream>>>(modv, wm_t + 512 * 512, b_mod + 512, hband + big, hva, mbuf, L_N, 512, 512, 1);
    k_gemm<<<dim3(4, L_N / 128), 256, 0, stream>>>(mbuf, whv_t, b_hv, nullptr, nullptr, hvb, L_N, 512, 512, 1);
    k_out<<<dim3(L_N / 4), 256, 0, stream>>>(hvb, w_out + 512 * 3, b_out + 3, out + (size_t)b * L_N * 3, 0);
    // kk=2
    k_gemm<<<dim3(4, L_N / 128), 256, 0, stream>>>(modv, wm_t + 2 * 512 * 512, b_mod + 1024, hband + 2 * big, hvb, mbuf, L_N, 512, 512, 1);
    k_gemm<<<dim3(4, L_N / 128), 256, 0, stream>>>(mbuf, whv_t + 512 * 512, b_hv + 512, nullptr, nullptr, hva, L_N, 512, 512, 1);
    k_out<<<dim3(L_N / 4), 256, 0, stream>>>(hva, w_out + 2 * 512 * 3, b_out + 6, out + (size_t)b * L_N * 3, 0);
  }
}

// Round 3
// 952.331 us; speedup vs baseline: 5.4269x; 1.1948x over previous
//
#include <hip/hip_runtime.h>

#define L_N   16384
#define B_N   4
#define M_N   256
#define HID_N 512
#define PI_F  3.14159265358979323846f

typedef short short8 __attribute__((ext_vector_type(8)));
typedef float f32x4 __attribute__((ext_vector_type(4)));

__device__ __forceinline__ ushort f2bf(float f) {
  uint u = __float_as_uint(f);
  uint r = u + 0x7FFF + ((u >> 16) & 1);
  return (ushort)(r >> 16);
}
__device__ __forceinline__ float bf2f(ushort s) {
  return __uint_as_float(((uint)s) << 16);
}
__device__ __forceinline__ void gld_lds16(const void* g, void* s) {
  __builtin_amdgcn_global_load_lds((const __attribute__((address_space(1))) void*)g,
                                   (__attribute__((address_space(3))) void*)s, 16, 0, 0);
}

// ---------- merged weight transpose: fp32 [R][C] -> bf16 [C][R], all weights in one grid ----------
__global__ __launch_bounds__(256) void k_wt_all(
    const float* __restrict__ w_query, const float* __restrict__ w_to_q,
    const float* __restrict__ w_to_kv, const float* __restrict__ w_to_out,
    const float* __restrict__ w_band, const float* __restrict__ w_mod,
    const float* __restrict__ w_hv,
    ushort* __restrict__ wq_t, ushort* __restrict__ wtq_t,
    ushort* __restrict__ wkv_t, ushort* __restrict__ wto_t,
    ushort* __restrict__ wb_t, ushort* __restrict__ wm_t, ushort* __restrict__ whv_t) {
  __shared__ float t[32][33];
  int tb = blockIdx.x;
  const float* in; ushort* out; int R, C;
  if (tb < 64)        { in = w_query;  out = wq_t;  R = 128; C = 512; }
  else if (tb < 128)  { tb -= 64;  in = w_to_q;   out = wtq_t; R = 512; C = 128; }
  else if (tb < 256)  { tb -= 128; in = w_to_kv;  out = wkv_t; R = 512; C = 256; }
  else if (tb < 320)  { tb -= 256; in = w_to_out; out = wto_t; R = 128; C = 512; }
  else if (tb < 512)  { tb -= 320; int kk = tb >> 6; tb &= 63;
                        in = w_band + (size_t)kk * 65536; out = wb_t + (size_t)kk * 65536; R = 128; C = 512; }
  else if (tb < 1280) { tb -= 512; int kk = tb >> 8; tb &= 255;
                        in = w_mod + (size_t)kk * 262144; out = wm_t + (size_t)kk * 262144; R = 512; C = 512; }
  else                { tb -= 1280; int kk = tb >> 8; tb &= 255;
                        in = w_hv + (size_t)kk * 262144; out = whv_t + (size_t)kk * 262144; R = 512; C = 512; }
  int nbx = C >> 5;
  int bx = (tb % nbx) * 32, by = (tb / nbx) * 32;
  int tx = threadIdx.x & 31, ty = threadIdx.x >> 5;
#pragma unroll
  for (int j = 0; j < 32; j += 8) t[ty + j][tx] = in[(size_t)(by + ty + j) * C + bx + tx];
  __syncthreads();
#pragma unroll
  for (int j = 0; j < 32; j += 8)
    out[(size_t)(bx + ty + j) * R + by + tx] = f2bf(t[tx][ty + j]);
}

// ---------- fp32 -> bf16 elementwise ----------
__global__ __launch_bounds__(256) void k_cvt(const float* __restrict__ in,
                                             ushort* __restrict__ out, int n4) {
  int i = blockIdx.x * 256 + threadIdx.x;
  if (i >= n4) return;
  float4 v = *(const float4*)&in[(size_t)i * 4];
  ushort* o = &out[(size_t)i * 4];
  o[0] = f2bf(v.x); o[1] = f2bf(v.y); o[2] = f2bf(v.z); o[3] = f2bf(v.w);
}

// ---------- gamma: [4 specs][L][128] bf16 ----------
__global__ __launch_bounds__(256) void k_gamma(const float* __restrict__ x,
                                               ushort* __restrict__ gout) {
  __shared__ float om[16];
  const float lgs[4] = {2.1072099696478683f, 2.1072099696478683f,
                        1.5051499783199058f, 0.9030899869919435f};
  int spec = blockIdx.y;
  float lg = lgs[spec];
  int tid = threadIdx.x;
  if (tid < 16) om[tid] = powf(10.0f, 1.0f + (float)tid * ((lg - 1.0f) * (1.0f / 15.0f)));
  __syncthreads();
  int l0 = blockIdx.x * 16;
  int idx0 = tid * 8;
  int row = idx0 >> 7, f0 = idx0 & 127;
  int c = f0 >> 5;
  float g = x[(size_t)(l0 + row) * 4 + c];
  float base = PI_F * g;
  int w0 = f0 & 31;
  bool is_cos = (w0 >= 16);
  short8 o;
#pragma unroll
  for (int j = 0; j < 8; ++j) {
    int jf = (w0 + j) & 15;
    float arg = base * om[jf];
    float v = is_cos ? __cosf(arg) : __sinf(arg);
    o[j] = (short)f2bf(v);
  }
  *(short8*)&gout[(size_t)spec * L_N * 128 + (size_t)(l0 + row) * 128 + f0] = o;
}

// ---------- t positions ----------
__global__ __launch_bounds__(256) void k_tpos(const float* __restrict__ x,
                                              const int* dD, const int* dH,
                                              const int* dW, const int* dT,
                                              float* __restrict__ tbuf) {
  int l = blockIdx.x * 256 + threadIdx.x;
  float g0 = x[(size_t)l * 4 + 0], g1 = x[(size_t)l * 4 + 1];
  float g2 = x[(size_t)l * 4 + 2], g3 = x[(size_t)l * 4 + 3];
  int Dd = dD[0], Hh = dH[0], Ww = dW[0], Tt = dT[0];
  int zi = (int)(g0 * (float)Dd), yi = (int)(g1 * (float)Hh);
  int xi = (int)(g2 * (float)Ww), ti = (int)(g3 * (float)Tt);
  int idx = ((ti * Dd + zi) * Hh + yi) * Ww + xi;
  tbuf[l] = (float)idx / (float)(Dd * Hh * Ww * Tt);
}

// ---------- generic bf16 MFMA GEMM, 128x128 tile, BK=64, 2-phase dbuf ----------
// C = [relu](A@Wt^T + bias [+ relu(G@Wb^T + bb)]) [+ add2]; z-batched via strides
template <int BAND>
__global__ __launch_bounds__(256) void k_gemm2(
    const ushort* __restrict__ A, long long sA,
    const ushort* __restrict__ Wt,
    const float* __restrict__ bias,
    const ushort* __restrict__ G, const ushort* __restrict__ Wb,
    const float* __restrict__ bb,
    const ushort* add2, long long sAdd2,
    ushort* C, long long sC,
    int N, int K, int do_relu) {
  __shared__ __align__(16) ushort As[2][128 * 64];
  __shared__ __align__(16) ushort Ws[2][128 * 64];
  int tid = threadIdx.x;
  int lane = tid & 63, wid = tid >> 6;
  int n0 = blockIdx.x * 128, r0 = blockIdx.y * 128;
  int z = blockIdx.z;
  A += (size_t)z * sA;
  C += (size_t)z * sC;
  const ushort* a2p = add2 ? add2 + (size_t)z * sAdd2 : nullptr;
  int wr = wid >> 1, wc = wid & 1;
  int ksm = K >> 6;
  int nt = ksm + (BAND ? 2 : 0);

  auto stage = [&](int buf, int t) {
    const ushort* sa; const ushort* sw; int lda, ldw, ka, kw;
    if (!BAND || t < ksm) {
      sa = A;  lda = K;   ka = t * 64;
      sw = Wt; ldw = K;   kw = t * 64;
    } else {
      int kb = (t - ksm) * 64;
      sa = G;  lda = 128; ka = kb;
      sw = Wb; ldw = 128; kw = kb;
    }
#pragma unroll
    for (int j = 0; j < 4; ++j) {
      int sig = j * 256 + wid * 64 + lane;
      int r = sig >> 3, ph = sig & 7, sl = ph ^ (r & 7);
      gld_lds16(&sa[(size_t)(r0 + r) * lda + ka + sl * 8], &As[buf][(size_t)(j * 256 + wid * 64) * 8]);
      gld_lds16(&sw[(size_t)(n0 + r) * ldw + kw + sl * 8], &Ws[buf][(size_t)(j * 256 + wid * 64) * 8]);
    }
  };

  f32x4 acc[4][4];
  f32x4 acc2[BAND ? 4 : 1][4];
#pragma unroll
  for (int i = 0; i < 4; ++i)
#pragma unroll
    for (int j = 0; j < 4; ++j) acc[i][j] = (f32x4)0.0f;
#pragma unroll
  for (int i = 0; i < (BAND ? 4 : 1); ++i)
#pragma unroll
    for (int j = 0; j < 4; ++j) acc2[i][j] = (f32x4)0.0f;

  stage(0, 0);
  __syncthreads();
  int cur = 0;
  for (int t = 0; t < nt; ++t) {
    if (t + 1 < nt) stage(cur ^ 1, t + 1);
    bool band_step = BAND && (t >= ksm);
#pragma unroll
    for (int ks = 0; ks < 2; ++ks) {
      short8 af[4], bg[4];
#pragma unroll
      for (int fm = 0; fm < 4; ++fm) {
        int row = wr * 64 + fm * 16 + (lane & 15);
        af[fm] = *(const short8*)&As[cur][row * 64 + (((ks * 4 + (lane >> 4)) ^ (row & 7)) * 8)];
      }
#pragma unroll
      for (int fn = 0; fn < 4; ++fn) {
        int nl = wc * 64 + fn * 16 + (lane & 15);
        bg[fn] = *(const short8*)&Ws[cur][nl * 64 + (((ks * 4 + (lane >> 4)) ^ (nl & 7)) * 8)];
      }
      if (band_step) {
#pragma unroll
        for (int fm = 0; fm < 4; ++fm)
#pragma unroll
          for (int fn = 0; fn < 4; ++fn)
            acc2[fm][fn] = __builtin_amdgcn_mfma_f32_16x16x32_bf16(af[fm], bg[fn], acc2[fm][fn], 0, 0, 0);
      } else {
#pragma unroll
        for (int fm = 0; fm < 4; ++fm)
#pragma unroll
          for (int fn = 0; fn < 4; ++fn)
            acc[fm][fn] = __builtin_amdgcn_mfma_f32_16x16x32_bf16(af[fm], bg[fn], acc[fm][fn], 0, 0, 0);
      }
    }
    __syncthreads();
    cur ^= 1;
  }

  // vectorized epilogue via LDS staging (reuse As/Ws regions)
  float* Ls  = (float*)&As[0][0];   // [32][132] f32
  float* Ls2 = (float*)&Ws[0][0];
  int row = tid >> 3;            // 0..31
  int c0 = (tid & 7) * 16;
#pragma unroll
  for (int fm = 0; fm < 4; ++fm) {
    if (fm) __syncthreads();
#pragma unroll
    for (int fn = 0; fn < 4; ++fn)
#pragma unroll
      for (int reg = 0; reg < 4; ++reg) {
        int lr = wr * 16 + (lane >> 4) * 4 + reg;
        int lc = wc * 64 + fn * 16 + (lane & 15);
        Ls[lr * 132 + lc] = acc[fm][fn][reg];
        if (BAND) Ls2[lr * 132 + lc] = acc2[fm][fn][reg];
      }
    __syncthreads();
    int gr = r0 + (row >> 4) * 64 + fm * 16 + (row & 15);
#pragma unroll
    for (int hh = 0; hh < 2; ++hh) {
      int cc = c0 + hh * 8;
      float v[8];
#pragma unroll
      for (int j = 0; j < 8; ++j) {
        v[j] = Ls[row * 132 + cc + j];
        if (bias) v[j] += bias[n0 + cc + j];
        if (BAND) v[j] += fmaxf(Ls2[row * 132 + cc + j] + bb[n0 + cc + j], 0.0f);
      }
      if (do_relu) {
#pragma unroll
        for (int j = 0; j < 8; ++j) v[j] = fmaxf(v[j], 0.0f);
      }
      if (a2p) {
        short8 a2 = *(const short8*)&a2p[(size_t)gr * N + n0 + cc];
#pragma unroll
        for (int j = 0; j < 8; ++j) v[j] += bf2f((ushort)a2[j]);
      }
      short8 ov;
#pragma unroll
      for (int j = 0; j < 8; ++j) ov[j] = (short)f2bf(v[j]);
      *(short8*)&C[(size_t)gr * N + n0 + cc] = ov;
    }
  }
}

// ---------- kv rearrange ----------
__global__ __launch_bounds__(256) void k_rearr(const ushort* __restrict__ kvtmp,
                                               ushort* __restrict__ kbuf,
                                               ushort* __restrict__ vtb) {
  int i = blockIdx.x * 256 + threadIdx.x;
  int col = i & 255, row = i >> 8;
  int b = row >> 8, m = row & 255;
  ushort v = kvtmp[i];
  if (col < 128)
    kbuf[((size_t)b * 256 + m) * 128 + col] = v;
  else
    vtb[(size_t)b * 128 * 256 + (size_t)(col - 128) * 256 + m] = v;
}

// ---------- MFMA attention per (b, head), z = batch ----------
__global__ __launch_bounds__(256) void k_attn_m(const ushort* __restrict__ qbuf,
                                                const float* __restrict__ tbuf,
                                                const ushort* __restrict__ kbuf,
                                                const ushort* __restrict__ vtb,
                                                ushort* __restrict__ attn) {
  __shared__ __align__(16) ushort Kt[256 * 64];
  __shared__ __align__(16) ushort Vt[64 * 256];
  __shared__ __align__(16) ushort Qs[64 * 64];
  __shared__ __align__(16) ushort Pw[4][16 * 40];
  __shared__ float ts[64];
  int tid = threadIdx.x;
  int lane = tid & 63, wid = tid >> 6;
  int l0 = blockIdx.x * 64;
  int h = blockIdx.y;
  int z = blockIdx.z;
  const ushort* kbuf_b = kbuf + (size_t)z * M_N * 128;
  const ushort* vtb_b = vtb + (size_t)z * 128 * M_N;
  ushort* attn_b = attn + (size_t)z * L_N * 128;
#pragma unroll
  for (int j = 0; j < 8; ++j) {
    int sig = j * 256 + wid * 64 + lane;
    int m = sig >> 3, ph = sig & 7, sl = ph ^ (m & 7);
    gld_lds16(&kbuf_b[(size_t)m * 128 + h * 64 + sl * 8], &Kt[(size_t)(j * 256 + wid * 64) * 8]);
  }
#pragma unroll
  for (int j = 0; j < 8; ++j) {
    int sig = j * 256 + wid * 64 + lane;
    int d = sig >> 5, ph = sig & 31, sl = ph ^ ((d & 7) << 2);
    gld_lds16(&vtb_b[(size_t)(h * 64 + d) * 256 + sl * 8], &Vt[(size_t)(j * 256 + wid * 64) * 8]);
  }
#pragma unroll
  for (int j = 0; j < 2; ++j) {
    int sig = j * 256 + wid * 64 + lane;
    int q = sig >> 3, ph = sig & 7, sl = ph ^ (q & 7);
    gld_lds16(&qbuf[(size_t)(l0 + q) * 128 + h * 64 + sl * 8], &Qs[(size_t)(j * 256 + wid * 64) * 8]);
  }
  if (tid < 64) ts[tid] = tbuf[l0 + tid];
  __syncthreads();

  f32x4 s_acc[16];
#pragma unroll
  for (int fn = 0; fn < 16; ++fn) s_acc[fn] = (f32x4)0.0f;
#pragma unroll
  for (int ks = 0; ks < 2; ++ks) {
    int qrow = wid * 16 + (lane & 15);
    short8 aq = *(const short8*)&Qs[qrow * 64 + (((ks * 4 + (lane >> 4)) ^ (qrow & 7)) * 8)];
#pragma unroll
    for (int fn = 0; fn < 16; ++fn) {
      int m = fn * 16 + (lane & 15);
      short8 bk = *(const short8*)&Kt[m * 64 + (((ks * 4 + (lane >> 4)) ^ (m & 7)) * 8)];
      s_acc[fn] = __builtin_amdgcn_mfma_f32_16x16x32_bf16(aq, bk, s_acc[fn], 0, 0, 0);
    }
  }
  float mx[4] = {-1e30f, -1e30f, -1e30f, -1e30f};
#pragma unroll
  for (int fn = 0; fn < 16; ++fn) {
#pragma unroll
    for (int reg = 0; reg < 4; ++reg) {
      int ql = wid * 16 + (lane >> 4) * 4 + reg;
      int m = fn * 16 + (lane & 15);
      float mp = ((float)m + 0.5f) * (1.0f / 256.0f);
      float d = ts[ql] - mp;
      float v = s_acc[fn][reg] * 0.125f - 10.0f * d * d;
      s_acc[fn][reg] = v;
      mx[reg] = fmaxf(mx[reg], v);
    }
  }
#pragma unroll
  for (int reg = 0; reg < 4; ++reg) {
    mx[reg] = fmaxf(mx[reg], __shfl_xor(mx[reg], 1));
    mx[reg] = fmaxf(mx[reg], __shfl_xor(mx[reg], 2));
    mx[reg] = fmaxf(mx[reg], __shfl_xor(mx[reg], 4));
    mx[reg] = fmaxf(mx[reg], __shfl_xor(mx[reg], 8));
  }
  float sm[4] = {0.0f, 0.0f, 0.0f, 0.0f};
#pragma unroll
  for (int fn = 0; fn < 16; ++fn) {
#pragma unroll
    for (int reg = 0; reg < 4; ++reg) {
      float e = __expf(s_acc[fn][reg] - mx[reg]);
      s_acc[fn][reg] = e;
      sm[reg] += e;
    }
  }
#pragma unroll
  for (int reg = 0; reg < 4; ++reg) {
    sm[reg] += __shfl_xor(sm[reg], 1);
    sm[reg] += __shfl_xor(sm[reg], 2);
    sm[reg] += __shfl_xor(sm[reg], 4);
    sm[reg] += __shfl_xor(sm[reg], 8);
  }
  float inv[4];
#pragma unroll
  for (int reg = 0; reg < 4; ++reg) inv[reg] = 1.0f / sm[reg];

  f32x4 o_acc[4];
#pragma unroll
  for (int fn = 0; fn < 4; ++fn) o_acc[fn] = (f32x4)0.0f;
  for (int kk = 0; kk < 8; ++kk) {
#pragma unroll
    for (int fp = 0; fp < 2; ++fp) {
      int fn = kk * 2 + fp;
#pragma unroll
      for (int reg = 0; reg < 4; ++reg) {
        int ql16 = (lane >> 4) * 4 + reg;
        int mc = fp * 16 + (lane & 15);
        Pw[wid][ql16 * 40 + mc] = f2bf(s_acc[fn][reg] * inv[reg]);
      }
    }
    asm volatile("s_waitcnt lgkmcnt(0)" ::: "memory");
    __builtin_amdgcn_sched_barrier(0);
    short8 pa = *(const short8*)&Pw[wid][(lane & 15) * 40 + (lane >> 4) * 8];
#pragma unroll
    for (int fn = 0; fn < 4; ++fn) {
      int dr = fn * 16 + (lane & 15);
      short8 vb = *(const short8*)&Vt[dr * 256 + (((kk * 4 + (lane >> 4)) ^ ((dr & 7) << 2)) * 8)];
      o_acc[fn] = __builtin_amdgcn_mfma_f32_16x16x32_bf16(pa, vb, o_acc[fn], 0, 0, 0);
    }
    asm volatile("s_waitcnt lgkmcnt(0)" ::: "memory");
    __builtin_amdgcn_sched_barrier(0);
  }
#pragma unroll
  for (int fn = 0; fn < 4; ++fn)
#pragma unroll
    for (int reg = 0; reg < 4; ++reg) {
      int ql = l0 + wid * 16 + (lane >> 4) * 4 + reg;
      attn_b[(size_t)ql * 128 + h * 64 + fn * 16 + (lane & 15)] = f2bf(o_acc[fn][reg]);
    }
}

// ---------- out accumulation ----------
__global__ __launch_bounds__(256) void k_out(const ushort* __restrict__ hv, long long sHv,
                                             const float* __restrict__ wo,
                                             const float* __restrict__ bo,
                                             float* outp, long long sOut, int init) {
  int tid = threadIdx.x;
  int z = blockIdx.z;
  hv += (size_t)z * sHv;
  outp += (size_t)z * sOut;
  int l = blockIdx.x * 4 + (tid >> 6);
  int lane = tid & 63;
  short8 v = *(const short8*)&hv[(size_t)l * HID_N + lane * 8];
  float a0 = 0.0f, a1 = 0.0f, a2 = 0.0f;
#pragma unroll
  for (int j = 0; j < 8; ++j) {
    float a = bf2f((ushort)v[j]);
    int hh = lane * 8 + j;
    a0 = fmaf(a, wo[hh * 3 + 0], a0);
    a1 = fmaf(a, wo[hh * 3 + 1], a1);
    a2 = fmaf(a, wo[hh * 3 + 2], a2);
  }
  for (int off = 32; off; off >>= 1) {
    a0 += __shfl_down(a0, off);
    a1 += __shfl_down(a1, off);
    a2 += __shfl_down(a2, off);
  }
  if (lane == 0) {
    float* p = &outp[(size_t)l * 3];
    if (init) { p[0] = a0 + bo[0]; p[1] = a1 + bo[1]; p[2] = a2 + bo[2]; }
    else      { p[0] += a0 + bo[0]; p[1] += a1 + bo[1]; p[2] += a2 + bo[2]; }
  }
}

extern "C" void kernel_launch(void* const* d_in, const int* in_sizes, int n_in,
                              void* d_out, int out_size, void* d_ws, size_t ws_size,
                              hipStream_t stream) {
  const float* x        = (const float*)d_in[0];
  const float* tokens   = (const float*)d_in[1];
  const float* w_query  = (const float*)d_in[2];
  const float* b_query  = (const float*)d_in[3];
  const float* w_to_q   = (const float*)d_in[4];
  const float* w_to_kv  = (const float*)d_in[5];
  const float* w_to_out = (const float*)d_in[6];
  const float* b_to_out = (const float*)d_in[7];
  const float* w_band   = (const float*)d_in[8];
  const float* b_band   = (const float*)d_in[9];
  const float* w_mod    = (const float*)d_in[10];
  const float* b_mod    = (const float*)d_in[11];
  const float* w_hv     = (const float*)d_in[12];
  const float* b_hv     = (const float*)d_in[13];
  const float* w_out    = (const float*)d_in[14];
  const float* b_out    = (const float*)d_in[15];
  const int* Dd = (const int*)d_in[16];
  const int* Hh = (const int*)d_in[17];
  const int* Ww = (const int*)d_in[18];
  const int* Tt = (const int*)d_in[19];
  float* out = (float*)d_out;

  ushort* W = (ushort*)d_ws;
  size_t o = 0;
  auto alloc = [&](size_t n) { ushort* p = W + o; o += n; return p; };
  const size_t big = (size_t)L_N * HID_N;   // 8388608 elems
  const size_t LQ = (size_t)L_N * 128;      // 2097152

  ushort* gamma  = alloc(4 * LQ);
  ushort* qb     = alloc(LQ);
  ushort* attnout= alloc(4 * LQ);
  ushort* tokb   = alloc((size_t)B_N * M_N * HID_N);
  ushort* kbuf   = alloc((size_t)B_N * M_N * 128);
  ushort* vtb    = alloc((size_t)B_N * 128 * M_N);
  ushort* wq_t   = alloc(512 * 128);
  ushort* wtq_t  = alloc(128 * 512);
  ushort* wkv_t  = alloc(256 * 512);
  ushort* wto_t  = alloc(512 * 128);
  ushort* wb_t   = alloc(3 * 512 * 128);
  ushort* wm_t   = alloc(3 * 512 * 512);
  ushort* whv_t  = alloc(2 * 512 * 512);
  float* tbuf    = (float*)alloc(L_N * 2);
  size_t base_u = o;

  // batched (z=4) if workspace allows, else per-batch serial
  bool batched = ws_size >= (base_u + 3 * 4 * big) * sizeof(ushort);
  size_t zb = batched ? 4 * big : big;
  ushort* modv = alloc(zb);
  ushort* hv   = alloc(zb);
  ushort* tmp  = alloc(zb);
  ushort* xq = hv;          // alias: xq dead before hv first written
  ushort* kvtmp = attnout;  // alias: kvtmp consumed before attnout written

  const long long SL = (long long)big;   // per-z stride for [L][512]
  const long long SQ = (long long)LQ;    // per-z stride for [L][128]

  // ---- prep ----
  k_wt_all<<<dim3(1792), 256, 0, stream>>>(w_query, w_to_q, w_to_kv, w_to_out, w_band, w_mod, w_hv,
                                           wq_t, wtq_t, wkv_t, wto_t, wb_t, wm_t, whv_t);
  k_cvt<<<dim3(512), 256, 0, stream>>>(tokens, tokb, B_N * M_N * HID_N / 4);
  k_gamma<<<dim3(L_N / 16, 4), 256, 0, stream>>>(x, gamma);
  k_tpos<<<dim3(L_N / 256), 256, 0, stream>>>(x, Dd, Hh, Ww, Tt, tbuf);

  // ---- shared pre-pass ----
  k_gemm2<0><<<dim3(4, 128, 1), 256, 0, stream>>>(gamma, 0, wq_t, b_query,
                                                  nullptr, nullptr, nullptr, nullptr, 0,
                                                  xq, 0, 512, 128, 1);
  k_gemm2<0><<<dim3(1, 128, 1), 256, 0, stream>>>(xq, 0, wtq_t, nullptr,
                                                  nullptr, nullptr, nullptr, nullptr, 0,
                                                  qb, 0, 128, 512, 0);
  k_gemm2<0><<<dim3(2, 8, 1), 256, 0, stream>>>(tokb, 0, wkv_t, nullptr,
                                                nullptr, nullptr, nullptr, nullptr, 0,
                                                kvtmp, 0, 256, 512, 0);
  k_rearr<<<dim3(1024), 256, 0, stream>>>(kvtmp, kbuf, vtb);
  k_attn_m<<<dim3(L_N / 64, 2, 4), 256, 0, stream>>>(qb, tbuf, kbuf, vtb, attnout);

  if (batched) {
    k_gemm2<0><<<dim3(4, 128, 4), 256, 0, stream>>>(attnout, SQ, wto_t, b_to_out,
                                                    nullptr, nullptr, nullptr, nullptr, 0,
                                                    modv, SL, 512, 128, 0);
    // kk=0: hv = relu(band0 + modv@wm0 + bm0)
    k_gemm2<1><<<dim3(4, 128, 4), 256, 0, stream>>>(modv, SL, wm_t, b_mod,
                                                    gamma + 1 * LQ, wb_t, b_band, nullptr, 0,
                                                    hv, SL, 512, 512, 1);
    k_out<<<dim3(L_N / 4, 1, 4), 256, 0, stream>>>(hv, SL, w_out, b_out, out, (long long)L_N * 3, 1);
    // kk=1: s1 = relu(band1 + modv@wm1 + bm1) + hv0 (in-place into hv)
    k_gemm2<1><<<dim3(4, 128, 4), 256, 0, stream>>>(modv, SL, wm_t + 262144, b_mod + 512,
                                                    gamma + 2 * LQ, wb_t + 65536, b_band + 512, hv, SL,
                                                    hv, SL, 512, 512, 1);
    k_gemm2<0><<<dim3(4, 128, 4), 256, 0, stream>>>(hv, SL, whv_t, b_hv,
                                                    nullptr, nullptr, nullptr, nullptr, 0,
                                                    tmp, SL, 512, 512, 1);
    k_out<<<dim3(L_N / 4, 1, 4), 256, 0, stream>>>(tmp, SL, w_out + 1536, b_out + 3, out, (long long)L_N * 3, 0);
    // kk=2: s2 = relu(band2 + modv@wm2 + bm2) + hv1 (in-place into tmp)
    k_gemm2<1><<<dim3(4, 128, 4), 256, 0, stream>>>(modv, SL, wm_t + 524288, b_mod + 1024,
                                                    gamma + 3 * LQ, wb_t + 131072, b_band + 1024, tmp, SL,
                                                    tmp, SL, 512, 512, 1);
    k_gemm2<0><<<dim3(4, 128, 4), 256, 0, stream>>>(tmp, SL, whv_t + 262144, b_hv + 512,
                                                    nullptr, nullptr, nullptr, nullptr, 0,
                                                    hv, SL, 512, 512, 1);
    k_out<<<dim3(L_N / 4, 1, 4), 256, 0, stream>>>(hv, SL, w_out + 3072, b_out + 6, out, (long long)L_N * 3, 0);
  } else {
    for (int b = 0; b < B_N; ++b) {
      float* outb = out + (size_t)b * L_N * 3;
      k_gemm2<0><<<dim3(4, 128, 1), 256, 0, stream>>>(attnout + (size_t)b * LQ, 0, wto_t, b_to_out,
                                                      nullptr, nullptr, nullptr, nullptr, 0,
                                                      modv, 0, 512, 128, 0);
      k_gemm2<1><<<dim3(4, 128, 1), 256, 0, stream>>>(modv, 0, wm_t, b_mod,
                                                      gamma + 1 * LQ, wb_t, b_band, nullptr, 0,
                                                      hv, 0, 512, 512, 1);
      k_out<<<dim3(L_N / 4, 1, 1), 256, 0, stream>>>(hv, 0, w_out, b_out, outb, 0, 1);
      k_gemm2<1><<<dim3(4, 128, 1), 256, 0, stream>>>(modv, 0, wm_t + 262144, b_mod + 512,
                                                      gamma + 2 * LQ, wb_t + 65536, b_band + 512, hv, 0,
                                                      hv, 0, 512, 512, 1);
      k_gemm2<0><<<dim3(4, 128, 1), 256, 0, stream>>>(hv, 0, whv_t, b_hv,
                                                      nullptr, nullptr, nullptr, nullptr, 0,
                                                      tmp, 0, 512, 512, 1);
      k_out<<<dim3(L_N / 4, 1, 1), 256, 0, stream>>>(tmp, 0, w_out + 1536, b_out + 3, outb, 0, 0);
      k_gemm2<1><<<dim3(4, 128, 1), 256, 0, stream>>>(modv, 0, wm_t + 524288, b_mod + 1024,
                                                      gamma + 3 * LQ, wb_t + 131072, b_band + 1024, tmp, 0,
                                                      tmp, 0, 512, 512, 1);
      k_gemm2<0><<<dim3(4, 128, 1), 256, 0, stream>>>(tmp, 0, whv_t + 262144, b_hv + 512,
                                                      nullptr, nullptr, nullptr, nullptr, 0,
                                                      hv, 0, 512, 512, 1);
      k_out<<<dim3(L_N / 4, 1, 1), 256, 0, stream>>>(hv, 0, w_out + 3072, b_out + 6, outb, 0, 0);
    }
  }
}

// Round 4
// 624.325 us; speedup vs baseline: 8.2781x; 1.5254x over previous
//
#include <hip/hip_runtime.h>

#define L_N   16384
#define B_N   4
#define M_N   256
#define HID_N 512
#define PI_F  3.14159265358979323846f

typedef short short8 __attribute__((ext_vector_type(8)));
typedef float f32x4 __attribute__((ext_vector_type(4)));

__device__ __forceinline__ ushort f2bf(float f) {
  uint u = __float_as_uint(f);
  uint r = u + 0x7FFF + ((u >> 16) & 1);
  return (ushort)(r >> 16);
}
__device__ __forceinline__ float bf2f(ushort s) {
  return __uint_as_float(((uint)s) << 16);
}
__device__ __forceinline__ void gld_lds16(const void* g, void* s) {
  __builtin_amdgcn_global_load_lds((const __attribute__((address_space(1))) void*)g,
                                   (__attribute__((address_space(3))) void*)s, 16, 0, 0);
}

// ---------- merged weight transpose: fp32 [R][C] -> bf16 [C][R] ----------
__global__ __launch_bounds__(256) void k_wt_all(
    const float* __restrict__ w_query, const float* __restrict__ w_to_q,
    const float* __restrict__ w_to_kv, const float* __restrict__ w_to_out,
    const float* __restrict__ w_band, const float* __restrict__ w_mod,
    const float* __restrict__ w_hv,
    ushort* __restrict__ wq_t, ushort* __restrict__ wtq_t,
    ushort* __restrict__ wkv_t, ushort* __restrict__ wto_t,
    ushort* __restrict__ wb_t, ushort* __restrict__ wm_t, ushort* __restrict__ whv_t) {
  __shared__ float t[32][33];
  int tb = blockIdx.x;
  const float* in; ushort* out; int R, C;
  if (tb < 64)        { in = w_query;  out = wq_t;  R = 128; C = 512; }
  else if (tb < 128)  { tb -= 64;  in = w_to_q;   out = wtq_t; R = 512; C = 128; }
  else if (tb < 256)  { tb -= 128; in = w_to_kv;  out = wkv_t; R = 512; C = 256; }
  else if (tb < 320)  { tb -= 256; in = w_to_out; out = wto_t; R = 128; C = 512; }
  else if (tb < 512)  { tb -= 320; int kk = tb >> 6; tb &= 63;
                        in = w_band + (size_t)kk * 65536; out = wb_t + (size_t)kk * 65536; R = 128; C = 512; }
  else if (tb < 1280) { tb -= 512; int kk = tb >> 8; tb &= 255;
                        in = w_mod + (size_t)kk * 262144; out = wm_t + (size_t)kk * 262144; R = 512; C = 512; }
  else                { tb -= 1280; int kk = tb >> 8; tb &= 255;
                        in = w_hv + (size_t)kk * 262144; out = whv_t + (size_t)kk * 262144; R = 512; C = 512; }
  int nbx = C >> 5;
  int bx = (tb % nbx) * 32, by = (tb / nbx) * 32;
  int tx = threadIdx.x & 31, ty = threadIdx.x >> 5;
#pragma unroll
  for (int j = 0; j < 32; j += 8) t[ty + j][tx] = in[(size_t)(by + ty + j) * C + bx + tx];
  __syncthreads();
#pragma unroll
  for (int j = 0; j < 32; j += 8)
    out[(size_t)(bx + ty + j) * R + by + tx] = f2bf(t[tx][ty + j]);
}

// ---------- fp32 -> bf16 elementwise ----------
__global__ __launch_bounds__(256) void k_cvt(const float* __restrict__ in,
                                             ushort* __restrict__ out, int n4) {
  int i = blockIdx.x * 256 + threadIdx.x;
  if (i >= n4) return;
  float4 v = *(const float4*)&in[(size_t)i * 4];
  ushort* o = &out[(size_t)i * 4];
  o[0] = f2bf(v.x); o[1] = f2bf(v.y); o[2] = f2bf(v.z); o[3] = f2bf(v.w);
}

// ---------- gamma: [4 specs][L][128] bf16 ----------
__global__ __launch_bounds__(256) void k_gamma(const float* __restrict__ x,
                                               ushort* __restrict__ gout) {
  __shared__ float om[16];
  const float lgs[4] = {2.1072099696478683f, 2.1072099696478683f,
                        1.5051499783199058f, 0.9030899869919435f};
  int spec = blockIdx.y;
  float lg = lgs[spec];
  int tid = threadIdx.x;
  if (tid < 16) om[tid] = powf(10.0f, 1.0f + (float)tid * ((lg - 1.0f) * (1.0f / 15.0f)));
  __syncthreads();
  int l0 = blockIdx.x * 16;
  int idx0 = tid * 8;
  int row = idx0 >> 7, f0 = idx0 & 127;
  int c = f0 >> 5;
  float g = x[(size_t)(l0 + row) * 4 + c];
  float base = PI_F * g;
  int w0 = f0 & 31;
  bool is_cos = (w0 >= 16);
  short8 o;
#pragma unroll
  for (int j = 0; j < 8; ++j) {
    int jf = (w0 + j) & 15;
    float arg = base * om[jf];
    float v = is_cos ? __cosf(arg) : __sinf(arg);
    o[j] = (short)f2bf(v);
  }
  *(short8*)&gout[(size_t)spec * L_N * 128 + (size_t)(l0 + row) * 128 + f0] = o;
}

// ---------- t positions ----------
__global__ __launch_bounds__(256) void k_tpos(const float* __restrict__ x,
                                              const int* dD, const int* dH,
                                              const int* dW, const int* dT,
                                              float* __restrict__ tbuf) {
  int l = blockIdx.x * 256 + threadIdx.x;
  float g0 = x[(size_t)l * 4 + 0], g1 = x[(size_t)l * 4 + 1];
  float g2 = x[(size_t)l * 4 + 2], g3 = x[(size_t)l * 4 + 3];
  int Dd = dD[0], Hh = dH[0], Ww = dW[0], Tt = dT[0];
  int zi = (int)(g0 * (float)Dd), yi = (int)(g1 * (float)Hh);
  int xi = (int)(g2 * (float)Ww), ti = (int)(g3 * (float)Tt);
  int idx = ((ti * Dd + zi) * Hh + yi) * Ww + xi;
  tbuf[l] = (float)idx / (float)(Dd * Hh * Ww * Tt);
}

// ---------- generic bf16 MFMA GEMM, 128x128 tile, BK=64, single-buffer LDS ----------
// C = [relu](A@Wt^T + bias + add1) [+ add2]; add1 pre-relu (z-independent), add2 post-relu (z-strided)
__global__ __launch_bounds__(256, 4) void k_gemm2(
    const ushort* __restrict__ A, long long sA,
    const ushort* __restrict__ Wt,
    const float* __restrict__ bias,
    const ushort* __restrict__ add1,
    const ushort* add2, long long sAdd2,
    ushort* C, long long sC,
    int N, int K, int do_relu) {
  __shared__ __align__(16) ushort S[128 * 64 * 2];   // 32 KB: As | Ws
  ushort* As = S;
  ushort* Ws = S + 128 * 64;
  int tid = threadIdx.x;
  int lane = tid & 63, wid = tid >> 6;
  int n0 = blockIdx.x * 128, r0 = blockIdx.y * 128;
  int z = blockIdx.z;
  A += (size_t)z * sA;
  C += (size_t)z * sC;
  const ushort* a2p = add2 ? add2 + (size_t)z * sAdd2 : nullptr;
  int wr = wid >> 1, wc = wid & 1;
  int ksm = K >> 6;

  f32x4 acc[4][4];
#pragma unroll
  for (int i = 0; i < 4; ++i)
#pragma unroll
    for (int j = 0; j < 4; ++j) acc[i][j] = (f32x4)0.0f;

  for (int t = 0; t < ksm; ++t) {
#pragma unroll
    for (int j = 0; j < 4; ++j) {
      int sig = j * 256 + wid * 64 + lane;
      int r = sig >> 3, ph = sig & 7, sl = ph ^ (r & 7);
      gld_lds16(&A[(size_t)(r0 + r) * K + t * 64 + sl * 8], &As[(size_t)(j * 256 + wid * 64) * 8]);
      gld_lds16(&Wt[(size_t)(n0 + r) * K + t * 64 + sl * 8], &Ws[(size_t)(j * 256 + wid * 64) * 8]);
    }
    __syncthreads();
#pragma unroll
    for (int ks = 0; ks < 2; ++ks) {
      short8 af[4], bg[4];
#pragma unroll
      for (int fm = 0; fm < 4; ++fm) {
        int row = wr * 64 + fm * 16 + (lane & 15);
        af[fm] = *(const short8*)&As[row * 64 + (((ks * 4 + (lane >> 4)) ^ (row & 7)) * 8)];
      }
#pragma unroll
      for (int fn = 0; fn < 4; ++fn) {
        int nl = wc * 64 + fn * 16 + (lane & 15);
        bg[fn] = *(const short8*)&Ws[nl * 64 + (((ks * 4 + (lane >> 4)) ^ (nl & 7)) * 8)];
      }
#pragma unroll
      for (int fm = 0; fm < 4; ++fm)
#pragma unroll
        for (int fn = 0; fn < 4; ++fn)
          acc[fm][fn] = __builtin_amdgcn_mfma_f32_16x16x32_bf16(af[fm], bg[fn], acc[fm][fn], 0, 0, 0);
    }
    __syncthreads();
  }

  // vectorized epilogue via LDS staging (32 KB union, one f32 pass per fm-chunk)
  float* Ls = (float*)S;   // [32][132] f32 = 16.9 KB
  int row = tid >> 3;
  int c0 = (tid & 7) * 16;
#pragma unroll
  for (int fm = 0; fm < 4; ++fm) {
    if (fm) __syncthreads();
#pragma unroll
    for (int fn = 0; fn < 4; ++fn)
#pragma unroll
      for (int reg = 0; reg < 4; ++reg) {
        int lr = wr * 16 + (lane >> 4) * 4 + reg;
        int lc = wc * 64 + fn * 16 + (lane & 15);
        Ls[lr * 132 + lc] = acc[fm][fn][reg];
      }
    __syncthreads();
    int gr = r0 + (row >> 4) * 64 + fm * 16 + (row & 15);
#pragma unroll
    for (int hh = 0; hh < 2; ++hh) {
      int cc = c0 + hh * 8;
      float v[8];
#pragma unroll
      for (int j = 0; j < 8; ++j) v[j] = Ls[row * 132 + cc + j];
      if (bias) {
#pragma unroll
        for (int j = 0; j < 8; ++j) v[j] += bias[n0 + cc + j];
      }
      if (add1) {
        short8 a1 = *(const short8*)&add1[(size_t)gr * N + n0 + cc];
#pragma unroll
        for (int j = 0; j < 8; ++j) v[j] += bf2f((ushort)a1[j]);
      }
      if (do_relu) {
#pragma unroll
        for (int j = 0; j < 8; ++j) v[j] = fmaxf(v[j], 0.0f);
      }
      if (a2p) {
        short8 a2 = *(const short8*)&a2p[(size_t)gr * N + n0 + cc];
#pragma unroll
        for (int j = 0; j < 8; ++j) v[j] += bf2f((ushort)a2[j]);
      }
      short8 ov;
#pragma unroll
      for (int j = 0; j < 8; ++j) ov[j] = (short)f2bf(v[j]);
      *(short8*)&C[(size_t)gr * N + n0 + cc] = ov;
    }
  }
}

// ---------- kv rearrange ----------
__global__ __launch_bounds__(256) void k_rearr(const ushort* __restrict__ kvtmp,
                                               ushort* __restrict__ kbuf,
                                               ushort* __restrict__ vtb) {
  int i = blockIdx.x * 256 + threadIdx.x;
  int col = i & 255, row = i >> 8;
  int b = row >> 8, m = row & 255;
  ushort v = kvtmp[i];
  if (col < 128)
    kbuf[((size_t)b * 256 + m) * 128 + col] = v;
  else
    vtb[(size_t)b * 128 * 256 + (size_t)(col - 128) * 256 + m] = v;
}

// ---------- MFMA attention per (b, head) ----------
__global__ __launch_bounds__(256) void k_attn_m(const ushort* __restrict__ qbuf,
                                                const float* __restrict__ tbuf,
                                                const ushort* __restrict__ kbuf,
                                                const ushort* __restrict__ vtb,
                                                ushort* __restrict__ attn) {
  __shared__ __align__(16) ushort Kt[256 * 64];
  __shared__ __align__(16) ushort Vt[64 * 256];
  __shared__ __align__(16) ushort Qs[64 * 64];
  __shared__ __align__(16) ushort Pw[4][16 * 40];
  __shared__ float ts[64];
  int tid = threadIdx.x;
  int lane = tid & 63, wid = tid >> 6;
  int l0 = blockIdx.x * 64;
  int h = blockIdx.y;
  int z = blockIdx.z;
  const ushort* kbuf_b = kbuf + (size_t)z * M_N * 128;
  const ushort* vtb_b = vtb + (size_t)z * 128 * M_N;
  ushort* attn_b = attn + (size_t)z * L_N * 128;
#pragma unroll
  for (int j = 0; j < 8; ++j) {
    int sig = j * 256 + wid * 64 + lane;
    int m = sig >> 3, ph = sig & 7, sl = ph ^ (m & 7);
    gld_lds16(&kbuf_b[(size_t)m * 128 + h * 64 + sl * 8], &Kt[(size_t)(j * 256 + wid * 64) * 8]);
  }
#pragma unroll
  for (int j = 0; j < 8; ++j) {
    int sig = j * 256 + wid * 64 + lane;
    int d = sig >> 5, ph = sig & 31, sl = ph ^ ((d & 7) << 2);
    gld_lds16(&vtb_b[(size_t)(h * 64 + d) * 256 + sl * 8], &Vt[(size_t)(j * 256 + wid * 64) * 8]);
  }
#pragma unroll
  for (int j = 0; j < 2; ++j) {
    int sig = j * 256 + wid * 64 + lane;
    int q = sig >> 3, ph = sig & 7, sl = ph ^ (q & 7);
    gld_lds16(&qbuf[(size_t)(l0 + q) * 128 + h * 64 + sl * 8], &Qs[(size_t)(j * 256 + wid * 64) * 8]);
  }
  if (tid < 64) ts[tid] = tbuf[l0 + tid];
  __syncthreads();

  f32x4 s_acc[16];
#pragma unroll
  for (int fn = 0; fn < 16; ++fn) s_acc[fn] = (f32x4)0.0f;
#pragma unroll
  for (int ks = 0; ks < 2; ++ks) {
    int qrow = wid * 16 + (lane & 15);
    short8 aq = *(const short8*)&Qs[qrow * 64 + (((ks * 4 + (lane >> 4)) ^ (qrow & 7)) * 8)];
#pragma unroll
    for (int fn = 0; fn < 16; ++fn) {
      int m = fn * 16 + (lane & 15);
      short8 bk = *(const short8*)&Kt[m * 64 + (((ks * 4 + (lane >> 4)) ^ (m & 7)) * 8)];
      s_acc[fn] = __builtin_amdgcn_mfma_f32_16x16x32_bf16(aq, bk, s_acc[fn], 0, 0, 0);
    }
  }
  float mx[4] = {-1e30f, -1e30f, -1e30f, -1e30f};
#pragma unroll
  for (int fn = 0; fn < 16; ++fn) {
#pragma unroll
    for (int reg = 0; reg < 4; ++reg) {
      int ql = wid * 16 + (lane >> 4) * 4 + reg;
      int m = fn * 16 + (lane & 15);
      float mp = ((float)m + 0.5f) * (1.0f / 256.0f);
      float d = ts[ql] - mp;
      float v = s_acc[fn][reg] * 0.125f - 10.0f * d * d;
      s_acc[fn][reg] = v;
      mx[reg] = fmaxf(mx[reg], v);
    }
  }
#pragma unroll
  for (int reg = 0; reg < 4; ++reg) {
    mx[reg] = fmaxf(mx[reg], __shfl_xor(mx[reg], 1));
    mx[reg] = fmaxf(mx[reg], __shfl_xor(mx[reg], 2));
    mx[reg] = fmaxf(mx[reg], __shfl_xor(mx[reg], 4));
    mx[reg] = fmaxf(mx[reg], __shfl_xor(mx[reg], 8));
  }
  float sm[4] = {0.0f, 0.0f, 0.0f, 0.0f};
#pragma unroll
  for (int fn = 0; fn < 16; ++fn) {
#pragma unroll
    for (int reg = 0; reg < 4; ++reg) {
      float e = __expf(s_acc[fn][reg] - mx[reg]);
      s_acc[fn][reg] = e;
      sm[reg] += e;
    }
  }
#pragma unroll
  for (int reg = 0; reg < 4; ++reg) {
    sm[reg] += __shfl_xor(sm[reg], 1);
    sm[reg] += __shfl_xor(sm[reg], 2);
    sm[reg] += __shfl_xor(sm[reg], 4);
    sm[reg] += __shfl_xor(sm[reg], 8);
  }
  float inv[4];
#pragma unroll
  for (int reg = 0; reg < 4; ++reg) inv[reg] = 1.0f / sm[reg];

  f32x4 o_acc[4];
#pragma unroll
  for (int fn = 0; fn < 4; ++fn) o_acc[fn] = (f32x4)0.0f;
  for (int kk = 0; kk < 8; ++kk) {
#pragma unroll
    for (int fp = 0; fp < 2; ++fp) {
      int fn = kk * 2 + fp;
#pragma unroll
      for (int reg = 0; reg < 4; ++reg) {
        int ql16 = (lane >> 4) * 4 + reg;
        int mc = fp * 16 + (lane & 15);
        Pw[wid][ql16 * 40 + mc] = f2bf(s_acc[fn][reg] * inv[reg]);
      }
    }
    asm volatile("s_waitcnt lgkmcnt(0)" ::: "memory");
    __builtin_amdgcn_sched_barrier(0);
    short8 pa = *(const short8*)&Pw[wid][(lane & 15) * 40 + (lane >> 4) * 8];
#pragma unroll
    for (int fn = 0; fn < 4; ++fn) {
      int dr = fn * 16 + (lane & 15);
      short8 vb = *(const short8*)&Vt[dr * 256 + (((kk * 4 + (lane >> 4)) ^ ((dr & 7) << 2)) * 8)];
      o_acc[fn] = __builtin_amdgcn_mfma_f32_16x16x32_bf16(pa, vb, o_acc[fn], 0, 0, 0);
    }
    asm volatile("s_waitcnt lgkmcnt(0)" ::: "memory");
    __builtin_amdgcn_sched_barrier(0);
  }
#pragma unroll
  for (int fn = 0; fn < 4; ++fn)
#pragma unroll
    for (int reg = 0; reg < 4; ++reg) {
      int ql = l0 + wid * 16 + (lane >> 4) * 4 + reg;
      attn_b[(size_t)ql * 128 + h * 64 + fn * 16 + (lane & 15)] = f2bf(o_acc[fn][reg]);
    }
}

// ---------- out accumulation ----------
__global__ __launch_bounds__(256) void k_out(const ushort* __restrict__ hv, long long sHv,
                                             const float* __restrict__ wo,
                                             const float* __restrict__ bo,
                                             float* outp, long long sOut, int init) {
  int tid = threadIdx.x;
  int z = blockIdx.z;
  hv += (size_t)z * sHv;
  outp += (size_t)z * sOut;
  int l = blockIdx.x * 4 + (tid >> 6);
  int lane = tid & 63;
  short8 v = *(const short8*)&hv[(size_t)l * HID_N + lane * 8];
  float a0 = 0.0f, a1 = 0.0f, a2 = 0.0f;
#pragma unroll
  for (int j = 0; j < 8; ++j) {
    float a = bf2f((ushort)v[j]);
    int hh = lane * 8 + j;
    a0 = fmaf(a, wo[hh * 3 + 0], a0);
    a1 = fmaf(a, wo[hh * 3 + 1], a1);
    a2 = fmaf(a, wo[hh * 3 + 2], a2);
  }
  for (int off = 32; off; off >>= 1) {
    a0 += __shfl_down(a0, off);
    a1 += __shfl_down(a1, off);
    a2 += __shfl_down(a2, off);
  }
  if (lane == 0) {
    float* p = &outp[(size_t)l * 3];
    if (init) { p[0] = a0 + bo[0]; p[1] = a1 + bo[1]; p[2] = a2 + bo[2]; }
    else      { p[0] += a0 + bo[0]; p[1] += a1 + bo[1]; p[2] += a2 + bo[2]; }
  }
}

extern "C" void kernel_launch(void* const* d_in, const int* in_sizes, int n_in,
                              void* d_out, int out_size, void* d_ws, size_t ws_size,
                              hipStream_t stream) {
  const float* x        = (const float*)d_in[0];
  const float* tokens   = (const float*)d_in[1];
  const float* w_query  = (const float*)d_in[2];
  const float* b_query  = (const float*)d_in[3];
  const float* w_to_q   = (const float*)d_in[4];
  const float* w_to_kv  = (const float*)d_in[5];
  const float* w_to_out = (const float*)d_in[6];
  const float* b_to_out = (const float*)d_in[7];
  const float* w_band   = (const float*)d_in[8];
  const float* b_band   = (const float*)d_in[9];
  const float* w_mod    = (const float*)d_in[10];
  const float* b_mod    = (const float*)d_in[11];
  const float* w_hv     = (const float*)d_in[12];
  const float* b_hv     = (const float*)d_in[13];
  const float* w_out    = (const float*)d_in[14];
  const float* b_out    = (const float*)d_in[15];
  const int* Dd = (const int*)d_in[16];
  const int* Hh = (const int*)d_in[17];
  const int* Ww = (const int*)d_in[18];
  const int* Tt = (const int*)d_in[19];
  float* out = (float*)d_out;

  ushort* W = (ushort*)d_ws;
  size_t o = 0;
  auto alloc = [&](size_t n) { ushort* p = W + o; o += n; return p; };
  const size_t big = (size_t)L_N * HID_N;   // 8388608
  const size_t LQ = (size_t)L_N * 128;      // 2097152

  ushort* gamma  = alloc(4 * LQ);
  ushort* qb     = alloc(LQ);
  ushort* attnout= alloc(4 * LQ);
  ushort* tokb   = alloc((size_t)B_N * M_N * HID_N);
  ushort* kbuf   = alloc((size_t)B_N * M_N * 128);
  ushort* vtb    = alloc((size_t)B_N * 128 * M_N);
  ushort* wq_t   = alloc(512 * 128);
  ushort* wtq_t  = alloc(128 * 512);
  ushort* wkv_t  = alloc(256 * 512);
  ushort* wto_t  = alloc(512 * 128);
  ushort* wb_t   = alloc(3 * 512 * 128);
  ushort* wm_t   = alloc(3 * 512 * 512);
  ushort* whv_t  = alloc(2 * 512 * 512);
  float* tbuf    = (float*)alloc(L_N * 2);
  ushort* hband  = alloc(3 * big);          // z-independent band activations
  size_t base_u = o;

  bool batched = ws_size >= (base_u + 3 * 4 * big) * sizeof(ushort);
  size_t zb = batched ? 4 * big : big;
  ushort* modv = alloc(zb);
  ushort* hv   = alloc(zb);
  ushort* tmp  = alloc(zb);
  ushort* xq = hv;          // alias: xq dead before hv first written
  ushort* kvtmp = attnout;  // alias: kvtmp consumed before attnout written

  const long long SL = (long long)big;
  const long long SQ = (long long)LQ;
  int NZ = batched ? 4 : 1;

  // ---- prep ----
  k_wt_all<<<dim3(1792), 256, 0, stream>>>(w_query, w_to_q, w_to_kv, w_to_out, w_band, w_mod, w_hv,
                                           wq_t, wtq_t, wkv_t, wto_t, wb_t, wm_t, whv_t);
  k_cvt<<<dim3(512), 256, 0, stream>>>(tokens, tokb, B_N * M_N * HID_N / 4);
  k_gamma<<<dim3(L_N / 16, 4), 256, 0, stream>>>(x, gamma);
  k_tpos<<<dim3(L_N / 256), 256, 0, stream>>>(x, Dd, Hh, Ww, Tt, tbuf);

  // ---- shared pre-pass ----
  k_gemm2<<<dim3(4, 128, 1), 256, 0, stream>>>(gamma, 0, wq_t, b_query, nullptr, nullptr, 0,
                                               xq, 0, 512, 128, 1);
  k_gemm2<<<dim3(1, 128, 1), 256, 0, stream>>>(xq, 0, wtq_t, nullptr, nullptr, nullptr, 0,
                                               qb, 0, 128, 512, 0);
  k_gemm2<<<dim3(2, 8, 1), 256, 0, stream>>>(tokb, 0, wkv_t, nullptr, nullptr, nullptr, 0,
                                             kvtmp, 0, 256, 512, 0);
  k_rearr<<<dim3(1024), 256, 0, stream>>>(kvtmp, kbuf, vtb);
  k_attn_m<<<dim3(L_N / 64, 2, 4), 256, 0, stream>>>(qb, tbuf, kbuf, vtb, attnout);
  for (int kk = 0; kk < 3; ++kk)
    k_gemm2<<<dim3(4, 128, 1), 256, 0, stream>>>(gamma + (size_t)(1 + kk) * LQ, 0,
                                                 wb_t + (size_t)kk * 65536, b_band + kk * 512,
                                                 nullptr, nullptr, 0,
                                                 hband + (size_t)kk * big, 0, 512, 128, 1);

  // ---- chain (z-batched when ws allows) ----
  for (int zb0 = 0; zb0 < B_N; zb0 += NZ) {
    const ushort* attnz = attnout + (size_t)zb0 * LQ;
    float* outz = out + (size_t)zb0 * L_N * 3;
    long long sOut = (long long)L_N * 3;
    k_gemm2<<<dim3(4, 128, NZ), 256, 0, stream>>>(attnz, SQ, wto_t, b_to_out, nullptr, nullptr, 0,
                                                  modv, SL, 512, 128, 0);
    // kk=0: hv = relu(hband0 + modv@wm0 + bm0)
    k_gemm2<<<dim3(4, 128, NZ), 256, 0, stream>>>(modv, SL, wm_t, b_mod, hband, nullptr, 0,
                                                  hv, SL, 512, 512, 1);
    k_out<<<dim3(L_N / 4, 1, NZ), 256, 0, stream>>>(hv, SL, w_out, b_out, outz, sOut, 1);
    // kk=1: hv = relu(hband1 + modv@wm1 + bm1) + hv   (in-place)
    k_gemm2<<<dim3(4, 128, NZ), 256, 0, stream>>>(modv, SL, wm_t + 262144, b_mod + 512,
                                                  hband + big, hv, SL, hv, SL, 512, 512, 1);
    k_gemm2<<<dim3(4, 128, NZ), 256, 0, stream>>>(hv, SL, whv_t, b_hv, nullptr, nullptr, 0,
                                                  tmp, SL, 512, 512, 1);
    k_out<<<dim3(L_N / 4, 1, NZ), 256, 0, stream>>>(tmp, SL, w_out + 1536, b_out + 3, outz, sOut, 0);
    // kk=2: tmp = relu(hband2 + modv@wm2 + bm2) + tmp (in-place)
    k_gemm2<<<dim3(4, 128, NZ), 256, 0, stream>>>(modv, SL, wm_t + 524288, b_mod + 1024,
                                                  hband + 2 * big, tmp, SL, tmp, SL, 512, 512, 1);
    k_gemm2<<<dim3(4, 128, NZ), 256, 0, stream>>>(tmp, SL, whv_t + 262144, b_hv + 512,
                                                  nullptr, nullptr, 0, hv, SL, 512, 512, 1);
    k_out<<<dim3(L_N / 4, 1, NZ), 256, 0, stream>>>(hv, SL, w_out + 3072, b_out + 6, outz, sOut, 0);
  }
}